// Round 1
// baseline (487.987 us; speedup 1.0000x reference)
//
#include <hip/hip_runtime.h>
#include <math.h>

#define NEG_SLOPE 0.2f
#define EPSBN 1e-5f

// ---------------- GEMM: C[M,N] = A[M,K] @ B[K,N], f32, 64x64 tile, BK=32 ----
__global__ __launch_bounds__(256) void gemm_f32_64x64(
    const float* __restrict__ A, const float* __restrict__ B, float* __restrict__ C,
    int M, int N, int K)
{
    __shared__ float As[32][64];   // As[k][m] (transposed store)
    __shared__ float Bs[32][64];   // Bs[k][n]
    const int tid = threadIdx.x;
    const int tx = tid & 15, ty = tid >> 4;
    const int rowBase = blockIdx.x * 64;
    const int colBase = blockIdx.y * 64;
    float acc[4][4] = {};
    const int lr = tid >> 3;          // 0..31
    const int lk = (tid & 7) * 4;     // k quad for A load
    const int bkr = tid >> 4;         // 0..15
    const int bc = (tid & 15) * 4;    // col quad for B load

    for (int kk = 0; kk < K; kk += 32) {
#pragma unroll
        for (int h = 0; h < 2; ++h) {
            int r = lr + h * 32;
            int grow = rowBase + r;
            float4 av = make_float4(0.f, 0.f, 0.f, 0.f);
            if (grow < M) av = *(const float4*)(A + (size_t)grow * K + kk + lk);
            As[lk + 0][r] = av.x; As[lk + 1][r] = av.y;
            As[lk + 2][r] = av.z; As[lk + 3][r] = av.w;
        }
#pragma unroll
        for (int h = 0; h < 2; ++h) {
            int kr = bkr + h * 16;
            float4 bv = *(const float4*)(B + (size_t)(kk + kr) * N + colBase + bc);
            *(float4*)&Bs[kr][bc] = bv;
        }
        __syncthreads();
#pragma unroll
        for (int k = 0; k < 32; ++k) {
            float4 av = *(const float4*)&As[k][ty * 4];
            float4 bv = *(const float4*)&Bs[k][tx * 4];
            float a[4] = {av.x, av.y, av.z, av.w};
            float b[4] = {bv.x, bv.y, bv.z, bv.w};
#pragma unroll
            for (int i = 0; i < 4; ++i)
#pragma unroll
                for (int j = 0; j < 4; ++j)
                    acc[i][j] = fmaf(a[i], b[j], acc[i][j]);
        }
        __syncthreads();
    }
#pragma unroll
    for (int i = 0; i < 4; ++i) {
        int grow = rowBase + ty * 4 + i;
        if (grow < M) {
            float4 v = make_float4(acc[i][0], acc[i][1], acc[i][2], acc[i][3]);
            *(float4*)(C + (size_t)grow * N + colBase + tx * 4) = v;
        }
    }
}

// ---------------- attention coefficients, layer 1 (2 heads, 128 ch) --------
__global__ __launch_bounds__(256) void attn_coef1(
    const float* __restrict__ h1, const float* __restrict__ a_src,
    const float* __restrict__ a_dst, float* __restrict__ asrc,
    float* __restrict__ adst, int Nn)
{
    int node = (int)((blockIdx.x * blockDim.x + threadIdx.x) >> 6);
    int lane = threadIdx.x & 63;
    if (node >= Nn) return;
    const float* hr = h1 + (size_t)node * 256;
    float v0 = hr[lane], v1 = hr[64 + lane], v2 = hr[128 + lane], v3 = hr[192 + lane];
    float ps0 = v0 * a_src[lane] + v1 * a_src[64 + lane];
    float ps1 = v2 * a_src[128 + lane] + v3 * a_src[192 + lane];
    float pd0 = v0 * a_dst[lane] + v1 * a_dst[64 + lane];
    float pd1 = v2 * a_dst[128 + lane] + v3 * a_dst[192 + lane];
    for (int off = 32; off; off >>= 1) {
        ps0 += __shfl_xor(ps0, off);
        ps1 += __shfl_xor(ps1, off);
        pd0 += __shfl_xor(pd0, off);
        pd1 += __shfl_xor(pd1, off);
    }
    if (lane == 0) {
        asrc[node * 2] = ps0; asrc[node * 2 + 1] = ps1;
        adst[node * 2] = pd0; adst[node * 2 + 1] = pd1;
    }
}

// ---------------- attention coefficients, layer 2 (1 head, 128 ch) ---------
__global__ __launch_bounds__(256) void attn_coef2(
    const float* __restrict__ h2, const float* __restrict__ a_src,
    const float* __restrict__ a_dst, float* __restrict__ asrc,
    float* __restrict__ adst, int Nn)
{
    int node = (int)((blockIdx.x * blockDim.x + threadIdx.x) >> 6);
    int lane = threadIdx.x & 63;
    if (node >= Nn) return;
    const float* hr = h2 + (size_t)node * 128;
    float v0 = hr[lane], v1 = hr[64 + lane];
    float ps = v0 * a_src[lane] + v1 * a_src[64 + lane];
    float pd = v0 * a_dst[lane] + v1 * a_dst[64 + lane];
    for (int off = 32; off; off >>= 1) {
        ps += __shfl_xor(ps, off);
        pd += __shfl_xor(pd, off);
    }
    if (lane == 0) { asrc[node] = ps; adst[node] = pd; }
}

// ---------------- CSR build -------------------------------------------------
__global__ void count_edges(const int* __restrict__ ei, int E, int Nn, int* __restrict__ counts)
{
    int e = blockIdx.x * blockDim.x + threadIdx.x;
    int E2 = E + Nn;
    if (e >= E2) return;
    int dst = (e < E) ? ei[E + e] : (e - E);
    atomicAdd(&counts[dst], 1);
}

__global__ __launch_bounds__(256) void scan_block(
    const int* __restrict__ counts, int* __restrict__ offs, int* __restrict__ bsum, int Nn)
{
    __shared__ int s[256];
    int i = blockIdx.x * 256 + threadIdx.x;
    int v = (i < Nn) ? counts[i] : 0;
    s[threadIdx.x] = v;
    __syncthreads();
    for (int off = 1; off < 256; off <<= 1) {
        int t = (threadIdx.x >= off) ? s[threadIdx.x - off] : 0;
        __syncthreads();
        s[threadIdx.x] += t;
        __syncthreads();
    }
    if (i < Nn) offs[i] = s[threadIdx.x] - v;          // exclusive within block
    if (threadIdx.x == 255) bsum[blockIdx.x] = s[255]; // block total
}

__global__ __launch_bounds__(256) void scan_tops(int* __restrict__ bsum, int* __restrict__ boff, int nb)
{
    __shared__ int s[256];
    int v = (threadIdx.x < nb) ? bsum[threadIdx.x] : 0;
    s[threadIdx.x] = v;
    __syncthreads();
    for (int off = 1; off < 256; off <<= 1) {
        int t = (threadIdx.x >= off) ? s[threadIdx.x - off] : 0;
        __syncthreads();
        s[threadIdx.x] += t;
        __syncthreads();
    }
    if (threadIdx.x < nb) boff[threadIdx.x] = s[threadIdx.x] - v;
}

__global__ void add_offsets(int* __restrict__ offs, const int* __restrict__ boff, int Nn, int E2)
{
    int i = blockIdx.x * blockDim.x + threadIdx.x;
    if (i < Nn) offs[i] += boff[i >> 8];
    if (i == 0) offs[Nn] = E2;
}

__global__ void fill_edges(const int* __restrict__ ei, int E, int Nn,
                           const int* __restrict__ offs, int* __restrict__ fill,
                           int* __restrict__ esrc)
{
    int e = blockIdx.x * blockDim.x + threadIdx.x;
    int E2 = E + Nn;
    if (e >= E2) return;
    int src, dst;
    if (e < E) { src = ei[e]; dst = ei[E + e]; }
    else       { src = e - E; dst = e - E; }
    int pos = offs[dst] + atomicAdd(&fill[dst], 1);
    esrc[pos] = src;
}

// ---------------- aggregation layer 1: wave per dst node --------------------
__global__ __launch_bounds__(256) void aggregate1(
    const float* __restrict__ h1, const float* __restrict__ asrc,
    const float* __restrict__ adst, const int* __restrict__ offs,
    const int* __restrict__ esrc, const float* __restrict__ b1,
    const float* __restrict__ gamma, const float* __restrict__ beta,
    const float* __restrict__ rm, const float* __restrict__ rv,
    float* __restrict__ x2, int Nn)
{
    int d = (int)((blockIdx.x * blockDim.x + threadIdx.x) >> 6);
    int lane = threadIdx.x & 63;
    if (d >= Nn) return;
    int beg = offs[d], end = offs[d + 1];
    float ad0 = adst[d * 2 + 0], ad1 = adst[d * 2 + 1];

    float m0 = -1e30f, m1 = -1e30f;
    for (int j = beg + lane; j < end; j += 64) {
        int s = esrc[j];
        float e0 = asrc[s * 2 + 0] + ad0; e0 = e0 > 0.f ? e0 : NEG_SLOPE * e0;
        float e1 = asrc[s * 2 + 1] + ad1; e1 = e1 > 0.f ? e1 : NEG_SLOPE * e1;
        m0 = fmaxf(m0, e0); m1 = fmaxf(m1, e1);
    }
    for (int off = 32; off; off >>= 1) {
        m0 = fmaxf(m0, __shfl_xor(m0, off));
        m1 = fmaxf(m1, __shfl_xor(m1, off));
    }
    float s0 = 0.f, s1 = 0.f;
    for (int j = beg + lane; j < end; j += 64) {
        int s = esrc[j];
        float e0 = asrc[s * 2 + 0] + ad0; e0 = e0 > 0.f ? e0 : NEG_SLOPE * e0;
        float e1 = asrc[s * 2 + 1] + ad1; e1 = e1 > 0.f ? e1 : NEG_SLOPE * e1;
        s0 += expf(e0 - m0); s1 += expf(e1 - m1);
    }
    for (int off = 32; off; off >>= 1) {
        s0 += __shfl_xor(s0, off);
        s1 += __shfl_xor(s1, off);
    }
    float rd0 = 1.f / s0, rd1 = 1.f / s1;

    int head = lane >> 5;                       // lanes 0-31: head0, 32-63: head1
    float mh = head ? m1 : m0;
    float rdh = head ? rd1 : rd0;
    float adh = head ? ad1 : ad0;
    int c4 = lane * 4;                          // channel base 0..252
    float ax = 0.f, ay = 0.f, az = 0.f, aw = 0.f;
    for (int j = beg; j < end; ++j) {
        int s = esrc[j];
        float e = asrc[s * 2 + head] + adh; e = e > 0.f ? e : NEG_SLOPE * e;
        float w = expf(e - mh) * rdh;
        float4 hv = *(const float4*)(h1 + (size_t)s * 256 + c4);
        ax = fmaf(w, hv.x, ax); ay = fmaf(w, hv.y, ay);
        az = fmaf(w, hv.z, az); aw = fmaf(w, hv.w, aw);
    }
    float vv[4] = {ax, ay, az, aw};
#pragma unroll
    for (int i = 0; i < 4; ++i) {
        int c = c4 + i;
        float v = vv[i] + b1[c];
        v = gamma[c] * (v - rm[c]) * rsqrtf(rv[c] + EPSBN) + beta[c];
        v = fmaxf(v, 0.f);
        x2[(size_t)d * 256 + c] = v;
    }
}

// ---------------- aggregation layer 2: wave per dst node (1 head, 128 ch) ---
__global__ __launch_bounds__(256) void aggregate2(
    const float* __restrict__ h2, const float* __restrict__ asrc,
    const float* __restrict__ adst, const int* __restrict__ offs,
    const int* __restrict__ esrc, const float* __restrict__ b2,
    const float* __restrict__ gamma, const float* __restrict__ beta,
    const float* __restrict__ rm, const float* __restrict__ rv,
    float* __restrict__ x3, int Nn)
{
    int d = (int)((blockIdx.x * blockDim.x + threadIdx.x) >> 6);
    int lane = threadIdx.x & 63;
    if (d >= Nn) return;
    int beg = offs[d], end = offs[d + 1];
    float ad = adst[d];

    float m = -1e30f;
    for (int j = beg + lane; j < end; j += 64) {
        int s = esrc[j];
        float e = asrc[s] + ad; e = e > 0.f ? e : NEG_SLOPE * e;
        m = fmaxf(m, e);
    }
    for (int off = 32; off; off >>= 1) m = fmaxf(m, __shfl_xor(m, off));
    float sden = 0.f;
    for (int j = beg + lane; j < end; j += 64) {
        int s = esrc[j];
        float e = asrc[s] + ad; e = e > 0.f ? e : NEG_SLOPE * e;
        sden += expf(e - m);
    }
    for (int off = 32; off; off >>= 1) sden += __shfl_xor(sden, off);
    float rd = 1.f / sden;

    int c2 = lane * 2;
    float ax = 0.f, ay = 0.f;
    for (int j = beg; j < end; ++j) {
        int s = esrc[j];
        float e = asrc[s] + ad; e = e > 0.f ? e : NEG_SLOPE * e;
        float w = expf(e - m) * rd;
        float2 hv = *(const float2*)(h2 + (size_t)s * 128 + c2);
        ax = fmaf(w, hv.x, ax); ay = fmaf(w, hv.y, ay);
    }
    float vv[2] = {ax, ay};
#pragma unroll
    for (int i = 0; i < 2; ++i) {
        int c = c2 + i;
        float v = vv[i] + b2[c];
        v = gamma[c] * (v - rm[c]) * rsqrtf(rv[c] + EPSBN) + beta[c];
        v = fmaxf(v, 0.f);
        x3[(size_t)d * 128 + c] = v;
    }
}

// ---------------- global max pool (values >= 0 so uint-bit atomicMax exact) -
__global__ void pool_max(const float* __restrict__ x3, const int* __restrict__ batch,
                         float* __restrict__ out, int Nn)
{
    int idx = blockIdx.x * blockDim.x + threadIdx.x;
    if (idx >= Nn * 128) return;
    int n = idx >> 7, c = idx & 127;
    int g = batch[n];
    atomicMax((unsigned int*)out + (size_t)g * 128 + c, __float_as_uint(x3[idx]));
}

// ---------------------------------------------------------------------------
extern "C" void kernel_launch(void* const* d_in, const int* in_sizes, int n_in,
                              void* d_out, int out_size, void* d_ws, size_t ws_size,
                              hipStream_t stream)
{
    const float* x   = (const float*)d_in[0];
    const int*   ei  = (const int*)d_in[1];
    const int*   bat = (const int*)d_in[2];
    const float* W1  = (const float*)d_in[3];
    const float* as1 = (const float*)d_in[4];
    const float* ad1 = (const float*)d_in[5];
    const float* b1  = (const float*)d_in[6];
    const float* g1  = (const float*)d_in[7];
    const float* be1 = (const float*)d_in[8];
    const float* rm1 = (const float*)d_in[9];
    const float* rv1 = (const float*)d_in[10];
    const float* W2  = (const float*)d_in[11];
    const float* as2 = (const float*)d_in[12];
    const float* ad2 = (const float*)d_in[13];
    const float* b2  = (const float*)d_in[14];
    const float* g2  = (const float*)d_in[15];
    const float* be2 = (const float*)d_in[16];
    const float* rm2 = (const float*)d_in[17];
    const float* rv2 = (const float*)d_in[18];
    float* out = (float*)d_out;

    const int Nn = in_sizes[0] / 128;
    const int E  = in_sizes[1] / 2;
    const int E2 = E + Nn;

    // workspace partition (256B aligned)
    char* p = (char*)d_ws;
    size_t off = 0;
    auto alloc = [&](size_t bytes) -> void* {
        void* r = p + off;
        off = (off + bytes + 255) & ~(size_t)255;
        return r;
    };
    float* h1    = (float*)alloc((size_t)Nn * 256 * 4);   // also reused as x3
    float* x2    = (float*)alloc((size_t)Nn * 256 * 4);
    float* h2    = (float*)alloc((size_t)Nn * 128 * 4);
    float* asrc1 = (float*)alloc((size_t)Nn * 2 * 4);
    float* adst1 = (float*)alloc((size_t)Nn * 2 * 4);
    float* asrc2 = (float*)alloc((size_t)Nn * 4);
    float* adst2 = (float*)alloc((size_t)Nn * 4);
    int*   counts= (int*)alloc((size_t)Nn * 4);
    int*   fillc = (int*)alloc((size_t)Nn * 4);
    int*   offs  = (int*)alloc((size_t)(Nn + 1) * 4);
    int*   bsum  = (int*)alloc(256 * 4);
    int*   boff  = (int*)alloc(256 * 4);
    int*   esrc  = (int*)alloc((size_t)E2 * 4);
    float* x3    = h1;  // alias: h1 dead after aggregate1

    const int nb = (Nn + 255) / 256;

    hipMemsetAsync(counts, 0, (size_t)Nn * 4, stream);
    hipMemsetAsync(fillc, 0, (size_t)Nn * 4, stream);
    hipMemsetAsync(d_out, 0, (size_t)out_size * 4, stream);

    // ---- layer 1 linear + attention coefficients
    gemm_f32_64x64<<<dim3((Nn + 63) / 64, 256 / 64), 256, 0, stream>>>(x, W1, h1, Nn, 256, 128);
    attn_coef1<<<(Nn + 3) / 4, 256, 0, stream>>>(h1, as1, ad1, asrc1, adst1, Nn);

    // ---- CSR build (reused by both layers)
    count_edges<<<(E2 + 255) / 256, 256, 0, stream>>>(ei, E, Nn, counts);
    scan_block<<<nb, 256, 0, stream>>>(counts, offs, bsum, Nn);
    scan_tops<<<1, 256, 0, stream>>>(bsum, boff, nb);
    add_offsets<<<(Nn + 255) / 256, 256, 0, stream>>>(offs, boff, Nn, E2);
    fill_edges<<<(E2 + 255) / 256, 256, 0, stream>>>(ei, E, Nn, offs, fillc, esrc);

    // ---- layer 1 aggregation + bias + BN + ReLU
    aggregate1<<<(Nn + 3) / 4, 256, 0, stream>>>(h1, asrc1, adst1, offs, esrc,
                                                 b1, g1, be1, rm1, rv1, x2, Nn);

    // ---- layer 2
    gemm_f32_64x64<<<dim3((Nn + 63) / 64, 128 / 64), 256, 0, stream>>>(x2, W2, h2, Nn, 128, 256);
    attn_coef2<<<(Nn + 3) / 4, 256, 0, stream>>>(h2, as2, ad2, asrc2, adst2, Nn);
    aggregate2<<<(Nn + 3) / 4, 256, 0, stream>>>(h2, asrc2, adst2, offs, esrc,
                                                 b2, g2, be2, rm2, rv2, x3, Nn);

    // ---- global max pool
    pool_max<<<((Nn * 128) + 255) / 256, 256, 0, stream>>>(x3, bat, out, Nn);
}

// Round 2
// 375.217 us; speedup vs baseline: 1.3005x; 1.3005x over previous
//
#include <hip/hip_runtime.h>
#include <hip/hip_bf16.h>
#include <math.h>

#define NEG_SLOPE 0.2f
#define EPSBN 1e-5f

__device__ __forceinline__ float bf2f(unsigned short u) {
    return __uint_as_float((unsigned)u << 16);
}

// ---------------- GEMM: C[M,N] = A[M,K] @ B[K,N], f32, 128x128 tile, BK=32 --
// Writes f32 C and (optionally) a bf16 copy for the gather passes.
__global__ __launch_bounds__(256) void gemm_f32_128x128(
    const float* __restrict__ A, const float* __restrict__ B,
    float* __restrict__ Cf, __hip_bfloat16* __restrict__ Cb,
    int M, int N, int K)
{
    __shared__ float As[32][128];   // [k][m]
    __shared__ float Bs[32][128];   // [k][n]
    const int tid = threadIdx.x;
    const int tx = tid & 15, ty = tid >> 4;
    const int rowBase = blockIdx.x * 128, colBase = blockIdx.y * 128;

    float acc[8][8] = {};

    const int ar  = tid >> 3;          // A: 8 lanes per row, rows step 32 per h
    const int ac4 = (tid & 7) * 4;     // k quad 0..28
    const int bkr = tid >> 5;          // B: k row 0..7, step 8 per h
    const int bc4 = (tid & 31) * 4;    // col quad 0..124

    for (int kk = 0; kk < K; kk += 32) {
#pragma unroll
        for (int h = 0; h < 4; ++h) {
            int r = ar + h * 32;
            int grow = rowBase + r;
            float4 av = (grow < M) ? *(const float4*)(A + (size_t)grow * K + kk + ac4)
                                   : make_float4(0.f, 0.f, 0.f, 0.f);
            As[ac4 + 0][r] = av.x; As[ac4 + 1][r] = av.y;
            As[ac4 + 2][r] = av.z; As[ac4 + 3][r] = av.w;
        }
#pragma unroll
        for (int h = 0; h < 4; ++h) {
            int kr = bkr + h * 8;
            *(float4*)&Bs[kr][bc4] = *(const float4*)(B + (size_t)(kk + kr) * N + colBase + bc4);
        }
        __syncthreads();
#pragma unroll
        for (int k = 0; k < 32; ++k) {
            float a[8], b[8];
            *(float4*)&a[0] = *(const float4*)&As[k][ty * 8];
            *(float4*)&a[4] = *(const float4*)&As[k][ty * 8 + 4];
            *(float4*)&b[0] = *(const float4*)&Bs[k][tx * 8];
            *(float4*)&b[4] = *(const float4*)&Bs[k][tx * 8 + 4];
#pragma unroll
            for (int i = 0; i < 8; ++i)
#pragma unroll
                for (int j = 0; j < 8; ++j)
                    acc[i][j] = fmaf(a[i], b[j], acc[i][j]);
        }
        __syncthreads();
    }

#pragma unroll
    for (int i = 0; i < 8; ++i) {
        int grow = rowBase + ty * 8 + i;
        if (grow >= M) continue;
        size_t off = (size_t)grow * N + colBase + tx * 8;
        *(float4*)(Cf + off)     = make_float4(acc[i][0], acc[i][1], acc[i][2], acc[i][3]);
        *(float4*)(Cf + off + 4) = make_float4(acc[i][4], acc[i][5], acc[i][6], acc[i][7]);
        if (Cb) {
            union { unsigned short us[8]; uint4 u4; } pk;
#pragma unroll
            for (int j = 0; j < 8; ++j)
                pk.us[j] = __bfloat16_as_ushort(__float2bfloat16(acc[i][j]));
            *(uint4*)(Cb + off) = pk.u4;
        }
    }
}

// ---------------- attention coefficients, layer 1 (2 heads, 128 ch) --------
__global__ __launch_bounds__(256) void attn_coef1(
    const float* __restrict__ h1, const float* __restrict__ a_src,
    const float* __restrict__ a_dst, float* __restrict__ asrc,
    float* __restrict__ adst, int Nn)
{
    int node = (int)((blockIdx.x * blockDim.x + threadIdx.x) >> 6);
    int lane = threadIdx.x & 63;
    if (node >= Nn) return;
    const float* hr = h1 + (size_t)node * 256;
    float v0 = hr[lane], v1 = hr[64 + lane], v2 = hr[128 + lane], v3 = hr[192 + lane];
    float ps0 = v0 * a_src[lane] + v1 * a_src[64 + lane];
    float ps1 = v2 * a_src[128 + lane] + v3 * a_src[192 + lane];
    float pd0 = v0 * a_dst[lane] + v1 * a_dst[64 + lane];
    float pd1 = v2 * a_dst[128 + lane] + v3 * a_dst[192 + lane];
    for (int off = 32; off; off >>= 1) {
        ps0 += __shfl_xor(ps0, off);
        ps1 += __shfl_xor(ps1, off);
        pd0 += __shfl_xor(pd0, off);
        pd1 += __shfl_xor(pd1, off);
    }
    if (lane == 0) {
        asrc[node * 2] = ps0; asrc[node * 2 + 1] = ps1;
        adst[node * 2] = pd0; adst[node * 2 + 1] = pd1;
    }
}

// ---------------- attention coefficients, layer 2 (1 head, 128 ch) ---------
__global__ __launch_bounds__(256) void attn_coef2(
    const float* __restrict__ h2, const float* __restrict__ a_src,
    const float* __restrict__ a_dst, float* __restrict__ asrc,
    float* __restrict__ adst, int Nn)
{
    int node = (int)((blockIdx.x * blockDim.x + threadIdx.x) >> 6);
    int lane = threadIdx.x & 63;
    if (node >= Nn) return;
    const float* hr = h2 + (size_t)node * 128;
    float v0 = hr[lane], v1 = hr[64 + lane];
    float ps = v0 * a_src[lane] + v1 * a_src[64 + lane];
    float pd = v0 * a_dst[lane] + v1 * a_dst[64 + lane];
    for (int off = 32; off; off >>= 1) {
        ps += __shfl_xor(ps, off);
        pd += __shfl_xor(pd, off);
    }
    if (lane == 0) { asrc[node] = ps; adst[node] = pd; }
}

// ---------------- CSR build -------------------------------------------------
__global__ void count_edges(const int* __restrict__ ei, int E, int Nn, int* __restrict__ counts)
{
    int e = blockIdx.x * blockDim.x + threadIdx.x;
    int E2 = E + Nn;
    if (e >= E2) return;
    int dst = (e < E) ? ei[E + e] : (e - E);
    atomicAdd(&counts[dst], 1);
}

__global__ __launch_bounds__(256) void scan_block(
    const int* __restrict__ counts, int* __restrict__ offs, int* __restrict__ bsum, int Nn)
{
    __shared__ int s[256];
    int i = blockIdx.x * 256 + threadIdx.x;
    int v = (i < Nn) ? counts[i] : 0;
    s[threadIdx.x] = v;
    __syncthreads();
    for (int off = 1; off < 256; off <<= 1) {
        int t = (threadIdx.x >= off) ? s[threadIdx.x - off] : 0;
        __syncthreads();
        s[threadIdx.x] += t;
        __syncthreads();
    }
    if (i < Nn) offs[i] = s[threadIdx.x] - v;
    if (threadIdx.x == 255) bsum[blockIdx.x] = s[255];
}

__global__ __launch_bounds__(256) void scan_tops(int* __restrict__ bsum, int* __restrict__ boff, int nb)
{
    __shared__ int s[256];
    int v = (threadIdx.x < nb) ? bsum[threadIdx.x] : 0;
    s[threadIdx.x] = v;
    __syncthreads();
    for (int off = 1; off < 256; off <<= 1) {
        int t = (threadIdx.x >= off) ? s[threadIdx.x - off] : 0;
        __syncthreads();
        s[threadIdx.x] += t;
        __syncthreads();
    }
    if (threadIdx.x < nb) boff[threadIdx.x] = s[threadIdx.x] - v;
}

__global__ void add_offsets(int* __restrict__ offs, const int* __restrict__ boff, int Nn, int E2)
{
    int i = blockIdx.x * blockDim.x + threadIdx.x;
    if (i < Nn) offs[i] += boff[i >> 8];
    if (i == 0) offs[Nn] = E2;
}

__global__ void fill_edges(const int* __restrict__ ei, int E, int Nn,
                           const int* __restrict__ offs, int* __restrict__ fill,
                           int* __restrict__ esrc)
{
    int e = blockIdx.x * blockDim.x + threadIdx.x;
    int E2 = E + Nn;
    if (e >= E2) return;
    int src, dst;
    if (e < E) { src = ei[e]; dst = ei[E + e]; }
    else       { src = e - E; dst = e - E; }
    int pos = offs[dst] + atomicAdd(&fill[dst], 1);
    esrc[pos] = src;
}

// ---------------- aggregation layer 1: wave per dst, bf16 gather ------------
__global__ __launch_bounds__(256) void aggregate1(
    const __hip_bfloat16* __restrict__ h1b, const float* __restrict__ asrc,
    const float* __restrict__ adst, const int* __restrict__ offs,
    const int* __restrict__ esrc, const float* __restrict__ b1,
    const float* __restrict__ gamma, const float* __restrict__ beta,
    const float* __restrict__ rm, const float* __restrict__ rv,
    float* __restrict__ x2, int Nn)
{
    int d = (int)((blockIdx.x * blockDim.x + threadIdx.x) >> 6);
    int lane = threadIdx.x & 63;
    if (d >= Nn) return;
    int beg = offs[d], end = offs[d + 1];
    float ad0 = adst[d * 2 + 0], ad1 = adst[d * 2 + 1];

    // pass 1: per-head max
    float m0 = -1e30f, m1 = -1e30f;
    for (int j = beg + lane; j < end; j += 64) {
        int s = esrc[j];
        float2 av = *(const float2*)(asrc + (size_t)s * 2);
        float e0 = av.x + ad0; e0 = e0 > 0.f ? e0 : NEG_SLOPE * e0;
        float e1 = av.y + ad1; e1 = e1 > 0.f ? e1 : NEG_SLOPE * e1;
        m0 = fmaxf(m0, e0); m1 = fmaxf(m1, e1);
    }
    for (int off = 32; off; off >>= 1) {
        m0 = fmaxf(m0, __shfl_xor(m0, off));
        m1 = fmaxf(m1, __shfl_xor(m1, off));
    }
    // pass 2: denom
    float s0 = 0.f, s1 = 0.f;
    for (int j = beg + lane; j < end; j += 64) {
        int s = esrc[j];
        float2 av = *(const float2*)(asrc + (size_t)s * 2);
        float e0 = av.x + ad0; e0 = e0 > 0.f ? e0 : NEG_SLOPE * e0;
        float e1 = av.y + ad1; e1 = e1 > 0.f ? e1 : NEG_SLOPE * e1;
        s0 += expf(e0 - m0); s1 += expf(e1 - m1);
    }
    for (int off = 32; off; off >>= 1) {
        s0 += __shfl_xor(s0, off);
        s1 += __shfl_xor(s1, off);
    }
    float rd0 = 1.f / s0, rd1 = 1.f / s1;

    // pass 3: weighted gather-sum, 64-edge chunks, shfl-broadcast weights
    const int head = lane >> 5;           // channels: c4 = lane*4, head = c4>>7
    const int c4 = lane * 4;
    float ax = 0.f, ay = 0.f, az = 0.f, aw = 0.f;
    for (int base = beg; base < end; base += 64) {
        int n = end - base; if (n > 64) n = 64;
        int sj = 0; float w0 = 0.f, w1 = 0.f;
        if (lane < n) {
            sj = esrc[base + lane];
            float2 av = *(const float2*)(asrc + (size_t)sj * 2);
            float e0 = av.x + ad0; e0 = e0 > 0.f ? e0 : NEG_SLOPE * e0;
            float e1 = av.y + ad1; e1 = e1 > 0.f ? e1 : NEG_SLOPE * e1;
            w0 = expf(e0 - m0) * rd0;
            w1 = expf(e1 - m1) * rd1;
        }
        int t = 0;
        for (; t + 1 < n; t += 2) {
            int sA = __shfl(sj, t), sB = __shfl(sj, t + 1);
            float a0 = __shfl(w0, t), a1 = __shfl(w1, t);
            float b0 = __shfl(w0, t + 1), b1v = __shfl(w1, t + 1);
            float wA = head ? a1 : a0;
            float wB = head ? b1v : b0;
            ushort4 hA = *(const ushort4*)(h1b + (size_t)sA * 256 + c4);
            ushort4 hB = *(const ushort4*)(h1b + (size_t)sB * 256 + c4);
            ax = fmaf(wA, bf2f(hA.x), ax); ay = fmaf(wA, bf2f(hA.y), ay);
            az = fmaf(wA, bf2f(hA.z), az); aw = fmaf(wA, bf2f(hA.w), aw);
            ax = fmaf(wB, bf2f(hB.x), ax); ay = fmaf(wB, bf2f(hB.y), ay);
            az = fmaf(wB, bf2f(hB.z), az); aw = fmaf(wB, bf2f(hB.w), aw);
        }
        if (t < n) {
            int sA = __shfl(sj, t);
            float a0 = __shfl(w0, t), a1 = __shfl(w1, t);
            float wA = head ? a1 : a0;
            ushort4 hA = *(const ushort4*)(h1b + (size_t)sA * 256 + c4);
            ax = fmaf(wA, bf2f(hA.x), ax); ay = fmaf(wA, bf2f(hA.y), ay);
            az = fmaf(wA, bf2f(hA.z), az); aw = fmaf(wA, bf2f(hA.w), aw);
        }
    }
    float vv[4] = {ax, ay, az, aw};
#pragma unroll
    for (int i = 0; i < 4; ++i) {
        int c = c4 + i;
        float v = vv[i] + b1[c];
        v = gamma[c] * (v - rm[c]) * rsqrtf(rv[c] + EPSBN) + beta[c];
        v = fmaxf(v, 0.f);
        x2[(size_t)d * 256 + c] = v;
    }
}

// ---------------- aggregation layer 2: wave per dst, bf16 gather ------------
__global__ __launch_bounds__(256) void aggregate2(
    const __hip_bfloat16* __restrict__ h2b, const float* __restrict__ asrc,
    const float* __restrict__ adst, const int* __restrict__ offs,
    const int* __restrict__ esrc, const float* __restrict__ b2,
    const float* __restrict__ gamma, const float* __restrict__ beta,
    const float* __restrict__ rm, const float* __restrict__ rv,
    float* __restrict__ x3, int Nn)
{
    int d = (int)((blockIdx.x * blockDim.x + threadIdx.x) >> 6);
    int lane = threadIdx.x & 63;
    if (d >= Nn) return;
    int beg = offs[d], end = offs[d + 1];
    float ad = adst[d];

    float m = -1e30f;
    for (int j = beg + lane; j < end; j += 64) {
        int s = esrc[j];
        float e = asrc[s] + ad; e = e > 0.f ? e : NEG_SLOPE * e;
        m = fmaxf(m, e);
    }
    for (int off = 32; off; off >>= 1) m = fmaxf(m, __shfl_xor(m, off));
    float sden = 0.f;
    for (int j = beg + lane; j < end; j += 64) {
        int s = esrc[j];
        float e = asrc[s] + ad; e = e > 0.f ? e : NEG_SLOPE * e;
        sden += expf(e - m);
    }
    for (int off = 32; off; off >>= 1) sden += __shfl_xor(sden, off);
    float rd = 1.f / sden;

    const int c2 = lane * 2;
    float ax = 0.f, ay = 0.f;
    for (int base = beg; base < end; base += 64) {
        int n = end - base; if (n > 64) n = 64;
        int sj = 0; float wj = 0.f;
        if (lane < n) {
            sj = esrc[base + lane];
            float e = asrc[sj] + ad; e = e > 0.f ? e : NEG_SLOPE * e;
            wj = expf(e - m) * rd;
        }
        int t = 0;
        for (; t + 1 < n; t += 2) {
            int sA = __shfl(sj, t), sB = __shfl(sj, t + 1);
            float wA = __shfl(wj, t), wB = __shfl(wj, t + 1);
            ushort2 hA = *(const ushort2*)(h2b + (size_t)sA * 128 + c2);
            ushort2 hB = *(const ushort2*)(h2b + (size_t)sB * 128 + c2);
            ax = fmaf(wA, bf2f(hA.x), ax); ay = fmaf(wA, bf2f(hA.y), ay);
            ax = fmaf(wB, bf2f(hB.x), ax); ay = fmaf(wB, bf2f(hB.y), ay);
        }
        if (t < n) {
            int sA = __shfl(sj, t);
            float wA = __shfl(wj, t);
            ushort2 hA = *(const ushort2*)(h2b + (size_t)sA * 128 + c2);
            ax = fmaf(wA, bf2f(hA.x), ax); ay = fmaf(wA, bf2f(hA.y), ay);
        }
    }
    float vv[2] = {ax, ay};
#pragma unroll
    for (int i = 0; i < 2; ++i) {
        int c = c2 + i;
        float v = vv[i] + b2[c];
        v = gamma[c] * (v - rm[c]) * rsqrtf(rv[c] + EPSBN) + beta[c];
        v = fmaxf(v, 0.f);
        x3[(size_t)d * 128 + c] = v;
    }
}

// ---------------- global max pool (values >= 0 so uint-bit atomicMax exact) -
__global__ void pool_max(const float* __restrict__ x3, const int* __restrict__ batch,
                         float* __restrict__ out, int Nn)
{
    int idx = blockIdx.x * blockDim.x + threadIdx.x;
    if (idx >= Nn * 128) return;
    int n = idx >> 7, c = idx & 127;
    int g = batch[n];
    atomicMax((unsigned int*)out + (size_t)g * 128 + c, __float_as_uint(x3[idx]));
}

// ---------------------------------------------------------------------------
extern "C" void kernel_launch(void* const* d_in, const int* in_sizes, int n_in,
                              void* d_out, int out_size, void* d_ws, size_t ws_size,
                              hipStream_t stream)
{
    const float* x   = (const float*)d_in[0];
    const int*   ei  = (const int*)d_in[1];
    const int*   bat = (const int*)d_in[2];
    const float* W1  = (const float*)d_in[3];
    const float* as1 = (const float*)d_in[4];
    const float* ad1 = (const float*)d_in[5];
    const float* b1  = (const float*)d_in[6];
    const float* g1  = (const float*)d_in[7];
    const float* be1 = (const float*)d_in[8];
    const float* rm1 = (const float*)d_in[9];
    const float* rv1 = (const float*)d_in[10];
    const float* W2  = (const float*)d_in[11];
    const float* as2 = (const float*)d_in[12];
    const float* ad2 = (const float*)d_in[13];
    const float* b2  = (const float*)d_in[14];
    const float* g2  = (const float*)d_in[15];
    const float* be2 = (const float*)d_in[16];
    const float* rm2 = (const float*)d_in[17];
    const float* rv2 = (const float*)d_in[18];
    float* out = (float*)d_out;

    const int Nn = in_sizes[0] / 128;
    const int E  = in_sizes[1] / 2;
    const int E2 = E + Nn;

    char* p = (char*)d_ws;
    size_t off = 0;
    auto alloc = [&](size_t bytes) -> void* {
        void* r = p + off;
        off = (off + bytes + 255) & ~(size_t)255;
        return r;
    };
    float*           h1    = (float*)alloc((size_t)Nn * 256 * 4);   // reused as x3
    float*           x2    = (float*)alloc((size_t)Nn * 256 * 4);
    float*           h2    = (float*)alloc((size_t)Nn * 128 * 4);
    __hip_bfloat16*  h1b   = (__hip_bfloat16*)alloc((size_t)Nn * 256 * 2);
    __hip_bfloat16*  h2b   = (__hip_bfloat16*)alloc((size_t)Nn * 128 * 2);
    float*           asrc1 = (float*)alloc((size_t)Nn * 2 * 4);
    float*           adst1 = (float*)alloc((size_t)Nn * 2 * 4);
    float*           asrc2 = (float*)alloc((size_t)Nn * 4);
    float*           adst2 = (float*)alloc((size_t)Nn * 4);
    int*             counts= (int*)alloc((size_t)Nn * 4);
    int*             fillc = (int*)alloc((size_t)Nn * 4);
    int*             offs  = (int*)alloc((size_t)(Nn + 1) * 4);
    int*             bsum  = (int*)alloc(256 * 4);
    int*             boff  = (int*)alloc(256 * 4);
    int*             esrc  = (int*)alloc((size_t)E2 * 4);
    float*           x3    = h1;  // alias: h1 dead after attn_coef1+aggregate1

    const int nb = (Nn + 255) / 256;

    hipMemsetAsync(counts, 0, (size_t)Nn * 4, stream);
    hipMemsetAsync(fillc, 0, (size_t)Nn * 4, stream);
    hipMemsetAsync(d_out, 0, (size_t)out_size * 4, stream);

    // ---- layer 1 linear (f32 + bf16 copy) + attention coefficients
    gemm_f32_128x128<<<dim3((Nn + 127) / 128, 2), 256, 0, stream>>>(x, W1, h1, h1b, Nn, 256, 128);
    attn_coef1<<<(Nn + 3) / 4, 256, 0, stream>>>(h1, as1, ad1, asrc1, adst1, Nn);

    // ---- CSR build (reused by both layers)
    count_edges<<<(E2 + 255) / 256, 256, 0, stream>>>(ei, E, Nn, counts);
    scan_block<<<nb, 256, 0, stream>>>(counts, offs, bsum, Nn);
    scan_tops<<<1, 256, 0, stream>>>(bsum, boff, nb);
    add_offsets<<<(Nn + 255) / 256, 256, 0, stream>>>(offs, boff, Nn, E2);
    fill_edges<<<(E2 + 255) / 256, 256, 0, stream>>>(ei, E, Nn, offs, fillc, esrc);

    // ---- layer 1 aggregation + bias + BN + ReLU
    aggregate1<<<(Nn + 3) / 4, 256, 0, stream>>>(h1b, asrc1, adst1, offs, esrc,
                                                 b1, g1, be1, rm1, rv1, x2, Nn);

    // ---- layer 2
    gemm_f32_128x128<<<dim3((Nn + 127) / 128, 1), 256, 0, stream>>>(x2, W2, h2, h2b, Nn, 128, 256);
    attn_coef2<<<(Nn + 3) / 4, 256, 0, stream>>>(h2, as2, ad2, asrc2, adst2, Nn);
    aggregate2<<<(Nn + 3) / 4, 256, 0, stream>>>(h2b, asrc2, adst2, offs, esrc,
                                                 b2, g2, be2, rm2, rv2, x3, Nn);

    // ---- global max pool
    pool_max<<<((Nn * 128) + 255) / 256, 256, 0, stream>>>(x3, bat, out, Nn);
}

// Round 3
// 371.871 us; speedup vs baseline: 1.3122x; 1.0090x over previous
//
#include <hip/hip_runtime.h>
#include <hip/hip_bf16.h>
#include <math.h>

#define NEG_SLOPE 0.2f
#define EPSBN 1e-5f

typedef __attribute__((ext_vector_type(8))) short bf16x8;
typedef __attribute__((ext_vector_type(4))) float f32x4;

__device__ __forceinline__ float bfu2f(unsigned u_lo16) { return __uint_as_float(u_lo16 << 16); }
__device__ __forceinline__ unsigned short f2bf(float f) {
    return __bfloat16_as_ushort(__float2bfloat16(f));
}
__device__ __forceinline__ void splitf(float v, unsigned short &h, unsigned short &l) {
    __hip_bfloat16 hb = __float2bfloat16(v);
    float r = v - __bfloat162float(hb);
    h = __bfloat16_as_ushort(hb);
    l = __bfloat16_as_ushort(__float2bfloat16(r));
}

// ---------------- split kernels --------------------------------------------
__global__ void split_x4(const float* __restrict__ X, unsigned short* __restrict__ Xh,
                         unsigned short* __restrict__ Xl, int total4)
{
    int i = blockIdx.x * blockDim.x + threadIdx.x;
    if (i >= total4) return;
    float4 v = *(const float4*)(X + (size_t)i * 4);
    unsigned short h[4], l[4];
    splitf(v.x, h[0], l[0]); splitf(v.y, h[1], l[1]);
    splitf(v.z, h[2], l[2]); splitf(v.w, h[3], l[3]);
    *(uint2*)(Xh + (size_t)i * 4) = *(uint2*)h;
    *(uint2*)(Xl + (size_t)i * 4) = *(uint2*)l;
}

// W [K,N] row-major -> transposed split planes [N,K]
__global__ void split_w_t(const float* __restrict__ W, unsigned short* __restrict__ Wh,
                          unsigned short* __restrict__ Wl, int K, int N)
{
    int idx = blockIdx.x * blockDim.x + threadIdx.x;  // = n*K + k
    if (idx >= K * N) return;
    int nn = idx / K, k = idx - nn * K;
    float v = W[(size_t)k * N + nn];
    unsigned short h, l; splitf(v, h, l);
    Wh[idx] = h; Wl[idx] = l;
}

// ---------------- MFMA GEMM: C[M,N] = A[M,K] @ B[K,N] ----------------------
// A as split bf16 planes [M,K]; B as TRANSPOSED split planes [N,K].
// 128x128 tile, 4 waves (2x2 of 64x64), BK=32, single-buffer LDS.
__global__ __launch_bounds__(256) void gemm_bf16_split(
    const unsigned short* __restrict__ Ah, const unsigned short* __restrict__ Al,
    const unsigned short* __restrict__ Bth, const unsigned short* __restrict__ Btl,
    unsigned short* __restrict__ Cb, int M, int N, int K)
{
    __shared__ unsigned short smem[4][128][32];  // Ah,Al,Bh,Bl tiles: 32 KiB
    const int tid = threadIdx.x;
    const int lane = tid & 63;
    const int wave = tid >> 6;
    const int fr = lane & 15, g = lane >> 4;
    const int wr = (wave >> 1) * 64, wc = (wave & 1) * 64;
    const int rowBase = blockIdx.x * 128, colBase = blockIdx.y * 128;

    f32x4 acc[4][4] = {};

    for (int kk = 0; kk < K; kk += 32) {
#pragma unroll
        for (int i = 0; i < 2; ++i) {
            int idx = tid + 256 * i;              // 0..511
            int r = idx >> 2, c = (idx & 3) * 8;  // c in ushorts
            int grow = rowBase + r;
            uint4 va_h, va_l;
            if (grow < M) {
                va_h = *(const uint4*)(Ah + (size_t)grow * K + kk + c);
                va_l = *(const uint4*)(Al + (size_t)grow * K + kk + c);
            } else {
                va_h = make_uint4(0, 0, 0, 0); va_l = make_uint4(0, 0, 0, 0);
            }
            *(uint4*)&smem[0][r][c] = va_h;
            *(uint4*)&smem[1][r][c] = va_l;
            int gcol = colBase + r;               // always < N (N multiple of 128)
            *(uint4*)&smem[2][r][c] = *(const uint4*)(Bth + (size_t)gcol * K + kk + c);
            *(uint4*)&smem[3][r][c] = *(const uint4*)(Btl + (size_t)gcol * K + kk + c);
        }
        __syncthreads();

        bf16x8 ah[4], al[4], bh[4], bl[4];
#pragma unroll
        for (int m = 0; m < 4; ++m) {
            ah[m] = *(const bf16x8*)&smem[0][wr + m * 16 + fr][g * 8];
            al[m] = *(const bf16x8*)&smem[1][wr + m * 16 + fr][g * 8];
        }
#pragma unroll
        for (int n = 0; n < 4; ++n) {
            bh[n] = *(const bf16x8*)&smem[2][wc + n * 16 + fr][g * 8];
            bl[n] = *(const bf16x8*)&smem[3][wc + n * 16 + fr][g * 8];
        }
#pragma unroll
        for (int m = 0; m < 4; ++m)
#pragma unroll
            for (int n = 0; n < 4; ++n) {
                acc[m][n] = __builtin_amdgcn_mfma_f32_16x16x32_bf16(ah[m], bh[n], acc[m][n], 0, 0, 0);
                acc[m][n] = __builtin_amdgcn_mfma_f32_16x16x32_bf16(ah[m], bl[n], acc[m][n], 0, 0, 0);
                acc[m][n] = __builtin_amdgcn_mfma_f32_16x16x32_bf16(al[m], bh[n], acc[m][n], 0, 0, 0);
            }
        __syncthreads();
    }

    // epilogue: LDS transpose (32 rows x 128 cols per m-step), coalesced bf16 stores
    float* Cs = (float*)&smem[0][0][0];           // [32][132] = 16.9 KiB
    const int rl_w = (wr >> 6) * 16;
#pragma unroll
    for (int m = 0; m < 4; ++m) {
        __syncthreads();
#pragma unroll
        for (int n = 0; n < 4; ++n)
#pragma unroll
            for (int j = 0; j < 4; ++j)
                Cs[(rl_w + g * 4 + j) * 132 + wc + n * 16 + fr] = acc[m][n][j];
        __syncthreads();
        int rl = tid >> 3, c16 = (tid & 7) * 16;
        int grow = rowBase + (rl >> 4) * 64 + m * 16 + (rl & 15);
        if (grow < M) {
            unsigned short tmp[16];
#pragma unroll
            for (int i = 0; i < 16; ++i) tmp[i] = f2bf(Cs[rl * 132 + c16 + i]);
            *(uint4*)(Cb + (size_t)grow * N + colBase + c16)     = *(uint4*)&tmp[0];
            *(uint4*)(Cb + (size_t)grow * N + colBase + c16 + 8) = *(uint4*)&tmp[8];
        }
    }
}

// ---------------- attention coefficients -----------------------------------
__global__ __launch_bounds__(256) void attn_coef1(
    const unsigned short* __restrict__ h1b, const float* __restrict__ a_src,
    const float* __restrict__ a_dst, float* __restrict__ asrc,
    float* __restrict__ adst, int Nn)
{
    int node = (int)((blockIdx.x * blockDim.x + threadIdx.x) >> 6);
    int lane = threadIdx.x & 63;
    if (node >= Nn) return;
    int c4 = lane * 4;
    uint2 hv = *(const uint2*)(h1b + (size_t)node * 256 + c4);
    float h0 = bfu2f(hv.x & 0xffff), h1 = __uint_as_float(hv.x & 0xffff0000u);
    float h2 = bfu2f(hv.y & 0xffff), h3 = __uint_as_float(hv.y & 0xffff0000u);
    float4 s4 = *(const float4*)(a_src + c4);
    float4 d4 = *(const float4*)(a_dst + c4);
    float ps = h0 * s4.x + h1 * s4.y + h2 * s4.z + h3 * s4.w;
    float pd = h0 * d4.x + h1 * d4.y + h2 * d4.z + h3 * d4.w;
    for (int off = 16; off; off >>= 1) { ps += __shfl_xor(ps, off); pd += __shfl_xor(pd, off); }
    if (lane == 0)  { asrc[node * 2 + 0] = ps; adst[node * 2 + 0] = pd; }
    if (lane == 32) { asrc[node * 2 + 1] = ps; adst[node * 2 + 1] = pd; }
}

__global__ __launch_bounds__(256) void attn_coef2(
    const unsigned short* __restrict__ h2b, const float* __restrict__ a_src,
    const float* __restrict__ a_dst, float* __restrict__ asrc,
    float* __restrict__ adst, int Nn)
{
    int node = (int)((blockIdx.x * blockDim.x + threadIdx.x) >> 6);
    int lane = threadIdx.x & 63;
    if (node >= Nn) return;
    int c2 = lane * 2;
    unsigned hv = *(const unsigned*)(h2b + (size_t)node * 128 + c2);
    float h0 = bfu2f(hv & 0xffff), h1 = __uint_as_float(hv & 0xffff0000u);
    float2 s2 = *(const float2*)(a_src + c2);
    float2 d2 = *(const float2*)(a_dst + c2);
    float ps = h0 * s2.x + h1 * s2.y;
    float pd = h0 * d2.x + h1 * d2.y;
    for (int off = 32; off; off >>= 1) { ps += __shfl_xor(ps, off); pd += __shfl_xor(pd, off); }
    if (lane == 0) { asrc[node] = ps; adst[node] = pd; }
}

// ---------------- CSR build -------------------------------------------------
__global__ void count_edges(const int* __restrict__ ei, int E, int Nn, int* __restrict__ counts)
{
    int e = blockIdx.x * blockDim.x + threadIdx.x;
    int E2 = E + Nn;
    if (e >= E2) return;
    int dst = (e < E) ? ei[E + e] : (e - E);
    atomicAdd(&counts[dst], 1);
}

__global__ __launch_bounds__(256) void scan_block(
    const int* __restrict__ counts, int* __restrict__ offs, int* __restrict__ bsum, int Nn)
{
    __shared__ int s[256];
    int i = blockIdx.x * 256 + threadIdx.x;
    int v = (i < Nn) ? counts[i] : 0;
    s[threadIdx.x] = v;
    __syncthreads();
    for (int off = 1; off < 256; off <<= 1) {
        int t = (threadIdx.x >= off) ? s[threadIdx.x - off] : 0;
        __syncthreads();
        s[threadIdx.x] += t;
        __syncthreads();
    }
    if (i < Nn) offs[i] = s[threadIdx.x] - v;
    if (threadIdx.x == 255) bsum[blockIdx.x] = s[255];
}

__global__ __launch_bounds__(256) void scan_tops(int* __restrict__ bsum, int* __restrict__ boff, int nb)
{
    __shared__ int s[256];
    int v = (threadIdx.x < nb) ? bsum[threadIdx.x] : 0;
    s[threadIdx.x] = v;
    __syncthreads();
    for (int off = 1; off < 256; off <<= 1) {
        int t = (threadIdx.x >= off) ? s[threadIdx.x - off] : 0;
        __syncthreads();
        s[threadIdx.x] += t;
        __syncthreads();
    }
    if (threadIdx.x < nb) boff[threadIdx.x] = s[threadIdx.x] - v;
}

__global__ void add_offsets(int* __restrict__ offs, const int* __restrict__ boff, int Nn, int E2)
{
    int i = blockIdx.x * blockDim.x + threadIdx.x;
    if (i < Nn) offs[i] += boff[i >> 8];
    if (i == 0) offs[Nn] = E2;
}

__global__ void fill_edges(const int* __restrict__ ei, int E, int Nn,
                           const int* __restrict__ offs, int* __restrict__ fill,
                           int* __restrict__ esrc)
{
    int e = blockIdx.x * blockDim.x + threadIdx.x;
    int E2 = E + Nn;
    if (e >= E2) return;
    int src, dst;
    if (e < E) { src = ei[e]; dst = ei[E + e]; }
    else       { src = e - E; dst = e - E; }
    int pos = offs[dst] + atomicAdd(&fill[dst], 1);
    esrc[pos] = src;
}

// ---------------- alpha precompute (softmax weights per edge) ---------------
__global__ __launch_bounds__(256) void alpha1(
    const float* __restrict__ asrc, const float* __restrict__ adst,
    const int* __restrict__ offs, const int* __restrict__ esrc,
    float* __restrict__ a1h0, float* __restrict__ a1h1, int Nn)
{
    int d = (int)((blockIdx.x * blockDim.x + threadIdx.x) >> 6);
    int lane = threadIdx.x & 63;
    if (d >= Nn) return;
    int beg = offs[d], end = offs[d + 1];
    float ad0 = adst[d * 2], ad1 = adst[d * 2 + 1];
    float m0 = -1e30f, m1 = -1e30f;
    for (int j = beg + lane; j < end; j += 64) {
        int s = esrc[j];
        float2 av = *(const float2*)(asrc + (size_t)s * 2);
        float e0 = av.x + ad0; e0 = e0 > 0.f ? e0 : NEG_SLOPE * e0;
        float e1 = av.y + ad1; e1 = e1 > 0.f ? e1 : NEG_SLOPE * e1;
        m0 = fmaxf(m0, e0); m1 = fmaxf(m1, e1);
    }
    for (int off = 32; off; off >>= 1) {
        m0 = fmaxf(m0, __shfl_xor(m0, off));
        m1 = fmaxf(m1, __shfl_xor(m1, off));
    }
    float s0 = 0.f, s1 = 0.f;
    for (int j = beg + lane; j < end; j += 64) {
        int s = esrc[j];
        float2 av = *(const float2*)(asrc + (size_t)s * 2);
        float e0 = av.x + ad0; e0 = e0 > 0.f ? e0 : NEG_SLOPE * e0;
        float e1 = av.y + ad1; e1 = e1 > 0.f ? e1 : NEG_SLOPE * e1;
        s0 += expf(e0 - m0); s1 += expf(e1 - m1);
    }
    for (int off = 32; off; off >>= 1) {
        s0 += __shfl_xor(s0, off);
        s1 += __shfl_xor(s1, off);
    }
    float rd0 = 1.f / s0, rd1 = 1.f / s1;
    for (int j = beg + lane; j < end; j += 64) {
        int s = esrc[j];
        float2 av = *(const float2*)(asrc + (size_t)s * 2);
        float e0 = av.x + ad0; e0 = e0 > 0.f ? e0 : NEG_SLOPE * e0;
        float e1 = av.y + ad1; e1 = e1 > 0.f ? e1 : NEG_SLOPE * e1;
        a1h0[j] = expf(e0 - m0) * rd0;
        a1h1[j] = expf(e1 - m1) * rd1;
    }
}

__global__ __launch_bounds__(256) void alpha2(
    const float* __restrict__ asrc, const float* __restrict__ adst,
    const int* __restrict__ offs, const int* __restrict__ esrc,
    float* __restrict__ a2, int Nn)
{
    int d = (int)((blockIdx.x * blockDim.x + threadIdx.x) >> 6);
    int lane = threadIdx.x & 63;
    if (d >= Nn) return;
    int beg = offs[d], end = offs[d + 1];
    float ad = adst[d];
    float m = -1e30f;
    for (int j = beg + lane; j < end; j += 64) {
        int s = esrc[j];
        float e = asrc[s] + ad; e = e > 0.f ? e : NEG_SLOPE * e;
        m = fmaxf(m, e);
    }
    for (int off = 32; off; off >>= 1) m = fmaxf(m, __shfl_xor(m, off));
    float sd = 0.f;
    for (int j = beg + lane; j < end; j += 64) {
        int s = esrc[j];
        float e = asrc[s] + ad; e = e > 0.f ? e : NEG_SLOPE * e;
        sd += expf(e - m);
    }
    for (int off = 32; off; off >>= 1) sd += __shfl_xor(sd, off);
    float rd = 1.f / sd;
    for (int j = beg + lane; j < end; j += 64) {
        int s = esrc[j];
        float e = asrc[s] + ad; e = e > 0.f ? e : NEG_SLOPE * e;
        a2[j] = expf(e - m) * rd;
    }
}

// ---------------- SpMM layer 1: 128-ch slice, 4 edges per wave-step ---------
// epilogue fuses bias+BN+ReLU and writes bf16 split planes for GEMM2
__global__ __launch_bounds__(256) void spmm1(
    const unsigned short* __restrict__ h1b, const float* __restrict__ alph,
    const int* __restrict__ offs, const int* __restrict__ esrc,
    const float* __restrict__ b1, const float* __restrict__ gamma,
    const float* __restrict__ beta, const float* __restrict__ rm,
    const float* __restrict__ rv, unsigned short* __restrict__ x2h,
    unsigned short* __restrict__ x2l, int slice, int Nn)
{
    int d = (int)((blockIdx.x * blockDim.x + threadIdx.x) >> 6);
    int lane = threadIdx.x & 63;
    if (d >= Nn) return;
    int beg = offs[d], end = offs[d + 1];
    const int sub = lane >> 4;            // edge subslot 0..3
    const int cl = (lane & 15) * 8;       // 8 channels
    const int cbase = slice * 128 + cl;
    float a0 = 0, a1 = 0, a2 = 0, a3 = 0, a4 = 0, a5 = 0, a6 = 0, a7 = 0;
    for (int base = beg; base < end; base += 64) {
        int n = end - base; if (n > 64) n = 64;
        int sj = 0; float wj = 0.f;
        if (lane < n) { sj = esrc[base + lane]; wj = alph[base + lane]; }
        for (int t = 0; t < n; t += 4) {
            int e = t + sub;
            int sA = __shfl(sj, e);
            float wA = __shfl(wj, e);
            if (e < n) {
                uint4 hv = *(const uint4*)(h1b + (size_t)sA * 256 + cbase);
                a0 = fmaf(wA, bfu2f(hv.x & 0xffff), a0);
                a1 = fmaf(wA, __uint_as_float(hv.x & 0xffff0000u), a1);
                a2 = fmaf(wA, bfu2f(hv.y & 0xffff), a2);
                a3 = fmaf(wA, __uint_as_float(hv.y & 0xffff0000u), a3);
                a4 = fmaf(wA, bfu2f(hv.z & 0xffff), a4);
                a5 = fmaf(wA, __uint_as_float(hv.z & 0xffff0000u), a5);
                a6 = fmaf(wA, bfu2f(hv.w & 0xffff), a6);
                a7 = fmaf(wA, __uint_as_float(hv.w & 0xffff0000u), a7);
            }
        }
    }
    float acc[8] = {a0, a1, a2, a3, a4, a5, a6, a7};
#pragma unroll
    for (int i = 0; i < 8; ++i) {
        acc[i] += __shfl_xor(acc[i], 32);
        acc[i] += __shfl_xor(acc[i], 16);
    }
    if (lane < 16) {
        unsigned short hh[8], ll[8];
#pragma unroll
        for (int i = 0; i < 8; ++i) {
            int c = cbase + i;
            float v = acc[i] + b1[c];
            v = gamma[c] * (v - rm[c]) * rsqrtf(rv[c] + EPSBN) + beta[c];
            v = fmaxf(v, 0.f);
            splitf(v, hh[i], ll[i]);
        }
        *(uint4*)(x2h + (size_t)d * 256 + cbase) = *(uint4*)&hh[0];
        *(uint4*)(x2l + (size_t)d * 256 + cbase) = *(uint4*)&ll[0];
    }
}

// ---------------- SpMM layer 2: 64-ch slice, 8 edges per wave-step ----------
__global__ __launch_bounds__(256) void spmm2(
    const unsigned short* __restrict__ h2b, const float* __restrict__ alph,
    const int* __restrict__ offs, const int* __restrict__ esrc,
    const float* __restrict__ b2, const float* __restrict__ gamma,
    const float* __restrict__ beta, const float* __restrict__ rm,
    const float* __restrict__ rv, float* __restrict__ x3, int slice, int Nn)
{
    int d = (int)((blockIdx.x * blockDim.x + threadIdx.x) >> 6);
    int lane = threadIdx.x & 63;
    if (d >= Nn) return;
    int beg = offs[d], end = offs[d + 1];
    const int sub = lane >> 3;            // edge subslot 0..7
    const int cl = (lane & 7) * 8;        // 8 channels
    const int cbase = slice * 64 + cl;
    float a0 = 0, a1 = 0, a2 = 0, a3 = 0, a4 = 0, a5 = 0, a6 = 0, a7 = 0;
    for (int base = beg; base < end; base += 64) {
        int n = end - base; if (n > 64) n = 64;
        int sj = 0; float wj = 0.f;
        if (lane < n) { sj = esrc[base + lane]; wj = alph[base + lane]; }
        for (int t = 0; t < n; t += 8) {
            int e = t + sub;
            int sA = __shfl(sj, e);
            float wA = __shfl(wj, e);
            if (e < n) {
                uint4 hv = *(const uint4*)(h2b + (size_t)sA * 128 + cbase);
                a0 = fmaf(wA, bfu2f(hv.x & 0xffff), a0);
                a1 = fmaf(wA, __uint_as_float(hv.x & 0xffff0000u), a1);
                a2 = fmaf(wA, bfu2f(hv.y & 0xffff), a2);
                a3 = fmaf(wA, __uint_as_float(hv.y & 0xffff0000u), a3);
                a4 = fmaf(wA, bfu2f(hv.z & 0xffff), a4);
                a5 = fmaf(wA, __uint_as_float(hv.z & 0xffff0000u), a5);
                a6 = fmaf(wA, bfu2f(hv.w & 0xffff), a6);
                a7 = fmaf(wA, __uint_as_float(hv.w & 0xffff0000u), a7);
            }
        }
    }
    float acc[8] = {a0, a1, a2, a3, a4, a5, a6, a7};
#pragma unroll
    for (int i = 0; i < 8; ++i) {
        acc[i] += __shfl_xor(acc[i], 32);
        acc[i] += __shfl_xor(acc[i], 16);
        acc[i] += __shfl_xor(acc[i], 8);
    }
    if (lane < 8) {
        float vv[8];
#pragma unroll
        for (int i = 0; i < 8; ++i) {
            int c = cbase + i;
            float v = acc[i] + b2[c];
            v = gamma[c] * (v - rm[c]) * rsqrtf(rv[c] + EPSBN) + beta[c];
            vv[i] = fmaxf(v, 0.f);
        }
        *(float4*)(x3 + (size_t)d * 128 + cbase)     = make_float4(vv[0], vv[1], vv[2], vv[3]);
        *(float4*)(x3 + (size_t)d * 128 + cbase + 4) = make_float4(vv[4], vv[5], vv[6], vv[7]);
    }
}

// ---------------- global max pool -------------------------------------------
__global__ void pool_max(const float* __restrict__ x3, const int* __restrict__ batch,
                         float* __restrict__ out, int Nn)
{
    int idx = blockIdx.x * blockDim.x + threadIdx.x;
    if (idx >= Nn * 128) return;
    int n = idx >> 7, c = idx & 127;
    int g = batch[n];
    atomicMax((unsigned int*)out + (size_t)g * 128 + c, __float_as_uint(x3[idx]));
}

// ---------------------------------------------------------------------------
extern "C" void kernel_launch(void* const* d_in, const int* in_sizes, int n_in,
                              void* d_out, int out_size, void* d_ws, size_t ws_size,
                              hipStream_t stream)
{
    const float* x   = (const float*)d_in[0];
    const int*   ei  = (const int*)d_in[1];
    const int*   bat = (const int*)d_in[2];
    const float* W1  = (const float*)d_in[3];
    const float* as1 = (const float*)d_in[4];
    const float* ad1 = (const float*)d_in[5];
    const float* b1  = (const float*)d_in[6];
    const float* g1  = (const float*)d_in[7];
    const float* be1 = (const float*)d_in[8];
    const float* rm1 = (const float*)d_in[9];
    const float* rv1 = (const float*)d_in[10];
    const float* W2  = (const float*)d_in[11];
    const float* as2 = (const float*)d_in[12];
    const float* ad2 = (const float*)d_in[13];
    const float* b2  = (const float*)d_in[14];
    const float* g2  = (const float*)d_in[15];
    const float* be2 = (const float*)d_in[16];
    const float* rm2 = (const float*)d_in[17];
    const float* rv2 = (const float*)d_in[18];
    float* out = (float*)d_out;

    const int Nn = in_sizes[0] / 128;
    const int E  = in_sizes[1] / 2;
    const int E2 = E + Nn;

    char* p = (char*)d_ws;
    size_t off = 0;
    auto alloc = [&](size_t bytes) -> void* {
        void* r = p + off;
        off = (off + bytes + 255) & ~(size_t)255;
        return r;
    };
    unsigned short* xh    = (unsigned short*)alloc((size_t)Nn * 128 * 2);
    unsigned short* xl    = (unsigned short*)alloc((size_t)Nn * 128 * 2);
    unsigned short* w1th  = (unsigned short*)alloc(256 * 128 * 2);
    unsigned short* w1tl  = (unsigned short*)alloc(256 * 128 * 2);
    unsigned short* w2th  = (unsigned short*)alloc(128 * 256 * 2);
    unsigned short* w2tl  = (unsigned short*)alloc(128 * 256 * 2);
    unsigned short* h1b   = (unsigned short*)alloc((size_t)Nn * 256 * 2);
    unsigned short* x2h   = (unsigned short*)alloc((size_t)Nn * 256 * 2);
    unsigned short* x2l   = (unsigned short*)alloc((size_t)Nn * 256 * 2);
    unsigned short* h2b   = (unsigned short*)alloc((size_t)Nn * 128 * 2);
    float*          x3    = (float*)alloc((size_t)Nn * 128 * 4);
    float*          asrc1 = (float*)alloc((size_t)Nn * 2 * 4);
    float*          adst1 = (float*)alloc((size_t)Nn * 2 * 4);
    float*          asrc2 = (float*)alloc((size_t)Nn * 4);
    float*          adst2 = (float*)alloc((size_t)Nn * 4);
    float*          a1h0  = (float*)alloc((size_t)E2 * 4);
    float*          a1h1  = (float*)alloc((size_t)E2 * 4);
    float*          a2e   = (float*)alloc((size_t)E2 * 4);
    int*            counts= (int*)alloc((size_t)Nn * 4);
    int*            fillc = (int*)alloc((size_t)Nn * 4);
    int*            offs  = (int*)alloc((size_t)(Nn + 1) * 4);
    int*            bsum  = (int*)alloc(256 * 4);
    int*            boff  = (int*)alloc(256 * 4);
    int*            esrc  = (int*)alloc((size_t)E2 * 4);

    const int nb = (Nn + 255) / 256;
    const int nwB = (Nn + 3) / 4;            // wave-per-node grids
    const int gmB = (Nn + 127) / 128;        // GEMM row blocks

    hipMemsetAsync(counts, 0, (size_t)Nn * 4, stream);
    hipMemsetAsync(fillc, 0, (size_t)Nn * 4, stream);
    hipMemsetAsync(d_out, 0, (size_t)out_size * 4, stream);

    // ---- input splits
    split_x4<<<(Nn * 128 / 4 + 255) / 256, 256, 0, stream>>>(x, xh, xl, Nn * 128 / 4);
    split_w_t<<<(128 * 256 + 255) / 256, 256, 0, stream>>>(W1, w1th, w1tl, 128, 256);
    split_w_t<<<(256 * 128 + 255) / 256, 256, 0, stream>>>(W2, w2th, w2tl, 256, 128);

    // ---- CSR build (independent of features)
    count_edges<<<(E2 + 255) / 256, 256, 0, stream>>>(ei, E, Nn, counts);
    scan_block<<<nb, 256, 0, stream>>>(counts, offs, bsum, Nn);
    scan_tops<<<1, 256, 0, stream>>>(bsum, boff, nb);
    add_offsets<<<(Nn + 255) / 256, 256, 0, stream>>>(offs, boff, Nn, E2);
    fill_edges<<<(E2 + 255) / 256, 256, 0, stream>>>(ei, E, Nn, offs, fillc, esrc);

    // ---- layer 1
    gemm_bf16_split<<<dim3(gmB, 2), 256, 0, stream>>>(xh, xl, w1th, w1tl, h1b, Nn, 256, 128);
    attn_coef1<<<nwB, 256, 0, stream>>>(h1b, as1, ad1, asrc1, adst1, Nn);
    alpha1<<<nwB, 256, 0, stream>>>(asrc1, adst1, offs, esrc, a1h0, a1h1, Nn);
    spmm1<<<nwB, 256, 0, stream>>>(h1b, a1h0, offs, esrc, b1, g1, be1, rm1, rv1, x2h, x2l, 0, Nn);
    spmm1<<<nwB, 256, 0, stream>>>(h1b, a1h1, offs, esrc, b1, g1, be1, rm1, rv1, x2h, x2l, 1, Nn);

    // ---- layer 2
    gemm_bf16_split<<<dim3(gmB, 1), 256, 0, stream>>>(x2h, x2l, w2th, w2tl, h2b, Nn, 128, 256);
    attn_coef2<<<nwB, 256, 0, stream>>>(h2b, as2, ad2, asrc2, adst2, Nn);
    alpha2<<<nwB, 256, 0, stream>>>(asrc2, adst2, offs, esrc, a2e, Nn);
    spmm2<<<nwB, 256, 0, stream>>>(h2b, a2e, offs, esrc, b2, g2, be2, rm2, rv2, x3, 0, Nn);
    spmm2<<<nwB, 256, 0, stream>>>(h2b, a2e, offs, esrc, b2, g2, be2, rm2, rv2, x3, 1, Nn);

    // ---- global max pool
    pool_max<<<((Nn * 128) + 255) / 256, 256, 0, stream>>>(x3, bat, out, Nn);
}

// Round 4
// 308.452 us; speedup vs baseline: 1.5821x; 1.2056x over previous
//
#include <hip/hip_runtime.h>
#include <hip/hip_bf16.h>
#include <math.h>

#define NEG_SLOPE 0.2f
#define EPSBN 1e-5f

typedef __attribute__((ext_vector_type(8))) short bf16x8;
typedef __attribute__((ext_vector_type(4))) float f32x4;

__device__ __forceinline__ float bfu2f(unsigned u_lo16) { return __uint_as_float(u_lo16 << 16); }
__device__ __forceinline__ unsigned short f2bf(float f) {
    return __bfloat16_as_ushort(__float2bfloat16(f));
}
__device__ __forceinline__ void splitf(float v, unsigned short &h, unsigned short &l) {
    __hip_bfloat16 hb = __float2bfloat16(v);
    float r = v - __bfloat162float(hb);
    h = __bfloat16_as_ushort(hb);
    l = __bfloat16_as_ushort(__float2bfloat16(r));
}

// ---------------- split kernels --------------------------------------------
__global__ void split_x4(const float* __restrict__ X, unsigned short* __restrict__ Xh,
                         unsigned short* __restrict__ Xl, int total4)
{
    int i = blockIdx.x * blockDim.x + threadIdx.x;
    if (i >= total4) return;
    float4 v = *(const float4*)(X + (size_t)i * 4);
    unsigned short h[4], l[4];
    splitf(v.x, h[0], l[0]); splitf(v.y, h[1], l[1]);
    splitf(v.z, h[2], l[2]); splitf(v.w, h[3], l[3]);
    *(uint2*)(Xh + (size_t)i * 4) = *(uint2*)h;
    *(uint2*)(Xl + (size_t)i * 4) = *(uint2*)l;
}

// both weights -> transposed split planes [N,K]
__global__ void split_w_both(const float* __restrict__ W1, const float* __restrict__ W2,
                             unsigned short* __restrict__ w1th, unsigned short* __restrict__ w1tl,
                             unsigned short* __restrict__ w2th, unsigned short* __restrict__ w2tl)
{
    int idx = blockIdx.x * blockDim.x + threadIdx.x;
    if (idx < 32768) {                      // W1 [128,256] -> [256,128]
        int nn = idx >> 7, k = idx & 127;
        unsigned short h, l; splitf(W1[(size_t)k * 256 + nn], h, l);
        w1th[idx] = h; w1tl[idx] = l;
    } else if (idx < 65536) {               // W2 [256,128] -> [128,256]
        int j = idx - 32768;
        int nn = j >> 8, k = j & 255;
        unsigned short h, l; splitf(W2[(size_t)k * 128 + nn], h, l);
        w2th[j] = h; w2tl[j] = l;
    }
}

// ---------------- MFMA GEMM + fused attention coefficients ------------------
// C[M,N] = A[M,K] @ B[K,N]; A split planes [M,K]; B transposed split [N,K].
// 128x128 tile, 4 waves, BK=32. Writes bf16 C and atomicAdds per-row
// dot(C_row, a_src|a_dst) into asrcOut/adstOut (pre-zeroed). head = col>>7.
__global__ __launch_bounds__(256) void gemm_bf16_split_attn(
    const unsigned short* __restrict__ Ah, const unsigned short* __restrict__ Al,
    const unsigned short* __restrict__ Bth, const unsigned short* __restrict__ Btl,
    unsigned short* __restrict__ Cb,
    const float* __restrict__ aSrc, const float* __restrict__ aDst,
    float* __restrict__ asrcOut, float* __restrict__ adstOut,
    int M, int N, int K, int heads)
{
    __shared__ unsigned short smem[4][128][32];  // Ah,Al,Bh,Bl tiles: 32 KiB
    const int tid = threadIdx.x;
    const int lane = tid & 63;
    const int wave = tid >> 6;
    const int fr = lane & 15, g = lane >> 4;
    const int wr = (wave >> 1) * 64, wc = (wave & 1) * 64;
    const int rowBase = blockIdx.x * 128, colBase = blockIdx.y * 128;

    f32x4 acc[4][4] = {};

    for (int kk = 0; kk < K; kk += 32) {
#pragma unroll
        for (int i = 0; i < 2; ++i) {
            int idx = tid + 256 * i;
            int r = idx >> 2, c = (idx & 3) * 8;
            int grow = rowBase + r;
            uint4 va_h, va_l;
            if (grow < M) {
                va_h = *(const uint4*)(Ah + (size_t)grow * K + kk + c);
                va_l = *(const uint4*)(Al + (size_t)grow * K + kk + c);
            } else {
                va_h = make_uint4(0, 0, 0, 0); va_l = make_uint4(0, 0, 0, 0);
            }
            *(uint4*)&smem[0][r][c] = va_h;
            *(uint4*)&smem[1][r][c] = va_l;
            int gcol = colBase + r;
            *(uint4*)&smem[2][r][c] = *(const uint4*)(Bth + (size_t)gcol * K + kk + c);
            *(uint4*)&smem[3][r][c] = *(const uint4*)(Btl + (size_t)gcol * K + kk + c);
        }
        __syncthreads();

        bf16x8 ah[4], al[4], bh[4], bl[4];
#pragma unroll
        for (int m = 0; m < 4; ++m) {
            ah[m] = *(const bf16x8*)&smem[0][wr + m * 16 + fr][g * 8];
            al[m] = *(const bf16x8*)&smem[1][wr + m * 16 + fr][g * 8];
        }
#pragma unroll
        for (int n = 0; n < 4; ++n) {
            bh[n] = *(const bf16x8*)&smem[2][wc + n * 16 + fr][g * 8];
            bl[n] = *(const bf16x8*)&smem[3][wc + n * 16 + fr][g * 8];
        }
#pragma unroll
        for (int m = 0; m < 4; ++m)
#pragma unroll
            for (int n = 0; n < 4; ++n) {
                acc[m][n] = __builtin_amdgcn_mfma_f32_16x16x32_bf16(ah[m], bh[n], acc[m][n], 0, 0, 0);
                acc[m][n] = __builtin_amdgcn_mfma_f32_16x16x32_bf16(ah[m], bl[n], acc[m][n], 0, 0, 0);
                acc[m][n] = __builtin_amdgcn_mfma_f32_16x16x32_bf16(al[m], bh[n], acc[m][n], 0, 0, 0);
            }
        __syncthreads();
    }

    // ---- fused attention coefficient partials (f32 accuracy)
    {
        const int head = colBase >> 7;
        float avs[4], avd[4];
#pragma unroll
        for (int n = 0; n < 4; ++n) {
            int col = colBase + wc + n * 16 + fr;
            avs[n] = aSrc[col]; avd[n] = aDst[col];
        }
#pragma unroll
        for (int m = 0; m < 4; ++m) {
            float ps[4], pd[4];
#pragma unroll
            for (int j = 0; j < 4; ++j) {
                ps[j] = acc[m][0][j] * avs[0] + acc[m][1][j] * avs[1]
                      + acc[m][2][j] * avs[2] + acc[m][3][j] * avs[3];
                pd[j] = acc[m][0][j] * avd[0] + acc[m][1][j] * avd[1]
                      + acc[m][2][j] * avd[2] + acc[m][3][j] * avd[3];
            }
#pragma unroll
            for (int off = 8; off; off >>= 1)
#pragma unroll
                for (int j = 0; j < 4; ++j) {
                    ps[j] += __shfl_xor(ps[j], off);
                    pd[j] += __shfl_xor(pd[j], off);
                }
            if (fr == 0) {
#pragma unroll
                for (int j = 0; j < 4; ++j) {
                    int grow = rowBase + wr + m * 16 + g * 4 + j;
                    if (grow < M) {
                        atomicAdd(asrcOut + (size_t)grow * heads + head, ps[j]);
                        atomicAdd(adstOut + (size_t)grow * heads + head, pd[j]);
                    }
                }
            }
        }
    }

    // ---- epilogue: LDS transpose, coalesced bf16 stores
    float* Cs = (float*)&smem[0][0][0];
    const int rl_w = (wr >> 6) * 16;
#pragma unroll
    for (int m = 0; m < 4; ++m) {
        __syncthreads();
#pragma unroll
        for (int n = 0; n < 4; ++n)
#pragma unroll
            for (int j = 0; j < 4; ++j)
                Cs[(rl_w + g * 4 + j) * 132 + wc + n * 16 + fr] = acc[m][n][j];
        __syncthreads();
        int rl = tid >> 3, c16 = (tid & 7) * 16;
        int grow = rowBase + (rl >> 4) * 64 + m * 16 + (rl & 15);
        if (grow < M) {
            unsigned short tmp[16];
#pragma unroll
            for (int i = 0; i < 16; ++i) tmp[i] = f2bf(Cs[rl * 132 + c16 + i]);
            *(uint4*)(Cb + (size_t)grow * N + colBase + c16)     = *(uint4*)&tmp[0];
            *(uint4*)(Cb + (size_t)grow * N + colBase + c16 + 8) = *(uint4*)&tmp[8];
        }
    }
}

// ---------------- CSR build -------------------------------------------------
__global__ void count_edges(const int* __restrict__ ei, int E, int Nn,
                            int* __restrict__ counts, int* __restrict__ erank)
{
    int e = blockIdx.x * blockDim.x + threadIdx.x;
    int E2 = E + Nn;
    if (e >= E2) return;
    int dst = (e < E) ? ei[E + e] : (e - E);
    erank[e] = atomicAdd(&counts[dst], 1);
}

__global__ __launch_bounds__(256) void scan_block(
    const int* __restrict__ counts, int* __restrict__ offs, int* __restrict__ bsum, int Nn)
{
    __shared__ int s[256];
    int i = blockIdx.x * 256 + threadIdx.x;
    int v = (i < Nn) ? counts[i] : 0;
    s[threadIdx.x] = v;
    __syncthreads();
    for (int off = 1; off < 256; off <<= 1) {
        int t = (threadIdx.x >= off) ? s[threadIdx.x - off] : 0;
        __syncthreads();
        s[threadIdx.x] += t;
        __syncthreads();
    }
    if (i < Nn) offs[i] = s[threadIdx.x] - v;
    if (threadIdx.x == 255) bsum[blockIdx.x] = s[255];
}

__global__ __launch_bounds__(256) void scan_tops(int* __restrict__ bsum, int* __restrict__ boff, int nb)
{
    __shared__ int s[256];
    int v = (threadIdx.x < nb) ? bsum[threadIdx.x] : 0;
    s[threadIdx.x] = v;
    __syncthreads();
    for (int off = 1; off < 256; off <<= 1) {
        int t = (threadIdx.x >= off) ? s[threadIdx.x - off] : 0;
        __syncthreads();
        s[threadIdx.x] += t;
        __syncthreads();
    }
    if (threadIdx.x < nb) boff[threadIdx.x] = s[threadIdx.x] - v;
}

__global__ void add_offsets(int* __restrict__ offs, const int* __restrict__ boff, int Nn, int E2)
{
    int i = blockIdx.x * blockDim.x + threadIdx.x;
    if (i < Nn) offs[i] += boff[i >> 8];
    if (i == 0) offs[Nn] = E2;
}

// atomic-free scatter using precomputed rank
__global__ void fill_edges(const int* __restrict__ ei, int E, int Nn,
                           const int* __restrict__ offs, const int* __restrict__ erank,
                           int* __restrict__ esrc)
{
    int e = blockIdx.x * blockDim.x + threadIdx.x;
    int E2 = E + Nn;
    if (e >= E2) return;
    int src, dst;
    if (e < E) { src = ei[e]; dst = ei[E + e]; }
    else       { src = e - E; dst = e - E; }
    esrc[offs[dst] + erank[e]] = src;
}

// ---------------- gather-FMA chunk helper ------------------------------------
template<int STEP, int ROWLEN>
__device__ __forceinline__ void edge_chunk_fma(
    int sj, float wj, int n, int sub, const unsigned short* __restrict__ hb,
    int cbase, float acc[8])
{
    for (int t = 0; t < n; t += STEP) {
        int e = t + sub;                   // e <= 63 always
        int sA = __shfl(sj, e);
        float wA = __shfl(wj, e);          // 0 for lanes beyond n -> no-op
        uint4 hv = *(const uint4*)(hb + (size_t)sA * ROWLEN + cbase);
        acc[0] = fmaf(wA, bfu2f(hv.x & 0xffff), acc[0]);
        acc[1] = fmaf(wA, __uint_as_float(hv.x & 0xffff0000u), acc[1]);
        acc[2] = fmaf(wA, bfu2f(hv.y & 0xffff), acc[2]);
        acc[3] = fmaf(wA, __uint_as_float(hv.y & 0xffff0000u), acc[3]);
        acc[4] = fmaf(wA, bfu2f(hv.z & 0xffff), acc[4]);
        acc[5] = fmaf(wA, __uint_as_float(hv.z & 0xffff0000u), acc[5]);
        acc[6] = fmaf(wA, bfu2f(hv.w & 0xffff), acc[6]);
        acc[7] = fmaf(wA, __uint_as_float(hv.w & 0xffff0000u), acc[7]);
    }
}

// ---------------- SpMM layer 1 slice 0 + fused softmax ----------------------
__global__ __launch_bounds__(256) void spmm1_s0(
    const unsigned short* __restrict__ h1b, const float* __restrict__ asrc,
    const float* __restrict__ adst, const int* __restrict__ offs,
    const int* __restrict__ esrc, float* __restrict__ a1h0, float* __restrict__ a1h1,
    const float* __restrict__ b1, const float* __restrict__ gamma,
    const float* __restrict__ beta, const float* __restrict__ rm,
    const float* __restrict__ rv, unsigned short* __restrict__ x2h,
    unsigned short* __restrict__ x2l, int Nn)
{
    int d = (int)((blockIdx.x * blockDim.x + threadIdx.x) >> 6);
    int lane = threadIdx.x & 63;
    if (d >= Nn) return;
    int beg = offs[d], end = offs[d + 1];
    int deg = end - beg;
    float ad0 = adst[d * 2], ad1 = adst[d * 2 + 1];
    const int sub = lane >> 4;
    const int cl = (lane & 15) * 8;
    float acc[8] = {};

    if (deg <= 64) {
        int sj = 0; float e0 = -1e30f, e1 = -1e30f;
        if (lane < deg) {
            sj = esrc[beg + lane];
            float2 av = *(const float2*)(asrc + (size_t)sj * 2);
            e0 = av.x + ad0; e0 = e0 > 0.f ? e0 : NEG_SLOPE * e0;
            e1 = av.y + ad1; e1 = e1 > 0.f ? e1 : NEG_SLOPE * e1;
        }
        float m0 = e0, m1 = e1;
        for (int off = 32; off; off >>= 1) {
            m0 = fmaxf(m0, __shfl_xor(m0, off));
            m1 = fmaxf(m1, __shfl_xor(m1, off));
        }
        float p0 = (lane < deg) ? expf(e0 - m0) : 0.f;
        float p1 = (lane < deg) ? expf(e1 - m1) : 0.f;
        float s0 = p0, s1 = p1;
        for (int off = 32; off; off >>= 1) {
            s0 += __shfl_xor(s0, off);
            s1 += __shfl_xor(s1, off);
        }
        float w0 = p0 * (1.f / s0), w1 = p1 * (1.f / s1);
        if (lane < deg) a1h1[beg + lane] = w1;
        edge_chunk_fma<4, 256>(sj, w0, deg, sub, h1b, cl, acc);
    } else {
        float m0 = -1e30f, m1 = -1e30f;
        for (int j = beg + lane; j < end; j += 64) {
            int s = esrc[j];
            float2 av = *(const float2*)(asrc + (size_t)s * 2);
            float e0 = av.x + ad0; e0 = e0 > 0.f ? e0 : NEG_SLOPE * e0;
            float e1 = av.y + ad1; e1 = e1 > 0.f ? e1 : NEG_SLOPE * e1;
            m0 = fmaxf(m0, e0); m1 = fmaxf(m1, e1);
        }
        for (int off = 32; off; off >>= 1) {
            m0 = fmaxf(m0, __shfl_xor(m0, off));
            m1 = fmaxf(m1, __shfl_xor(m1, off));
        }
        float s0 = 0.f, s1 = 0.f;
        for (int j = beg + lane; j < end; j += 64) {
            int s = esrc[j];
            float2 av = *(const float2*)(asrc + (size_t)s * 2);
            float e0 = av.x + ad0; e0 = e0 > 0.f ? e0 : NEG_SLOPE * e0;
            float e1 = av.y + ad1; e1 = e1 > 0.f ? e1 : NEG_SLOPE * e1;
            s0 += expf(e0 - m0); s1 += expf(e1 - m1);
        }
        for (int off = 32; off; off >>= 1) {
            s0 += __shfl_xor(s0, off);
            s1 += __shfl_xor(s1, off);
        }
        float rd0 = 1.f / s0, rd1 = 1.f / s1;
        for (int j = beg + lane; j < end; j += 64) {
            int s = esrc[j];
            float2 av = *(const float2*)(asrc + (size_t)s * 2);
            float e0 = av.x + ad0; e0 = e0 > 0.f ? e0 : NEG_SLOPE * e0;
            float e1 = av.y + ad1; e1 = e1 > 0.f ? e1 : NEG_SLOPE * e1;
            a1h0[j] = expf(e0 - m0) * rd0;
            a1h1[j] = expf(e1 - m1) * rd1;
        }
        for (int base = beg; base < end; base += 64) {
            int nc = end - base; if (nc > 64) nc = 64;
            int sj = 0; float wj = 0.f;
            if (lane < nc) { sj = esrc[base + lane]; wj = a1h0[base + lane]; }
            edge_chunk_fma<4, 256>(sj, wj, nc, sub, h1b, cl, acc);
        }
    }
#pragma unroll
    for (int i = 0; i < 8; ++i) {
        acc[i] += __shfl_xor(acc[i], 32);
        acc[i] += __shfl_xor(acc[i], 16);
    }
    if (lane < 16) {
        unsigned short hh[8], ll[8];
#pragma unroll
        for (int i = 0; i < 8; ++i) {
            int c = cl + i;
            float v = acc[i] + b1[c];
            v = gamma[c] * (v - rm[c]) * rsqrtf(rv[c] + EPSBN) + beta[c];
            v = fmaxf(v, 0.f);
            splitf(v, hh[i], ll[i]);
        }
        *(uint4*)(x2h + (size_t)d * 256 + cl) = *(uint4*)&hh[0];
        *(uint4*)(x2l + (size_t)d * 256 + cl) = *(uint4*)&ll[0];
    }
}

// ---------------- SpMM layer 1 slice 1 (weights from a1h1) ------------------
__global__ __launch_bounds__(256) void spmm1_s1(
    const unsigned short* __restrict__ h1b, const float* __restrict__ alph,
    const int* __restrict__ offs, const int* __restrict__ esrc,
    const float* __restrict__ b1, const float* __restrict__ gamma,
    const float* __restrict__ beta, const float* __restrict__ rm,
    const float* __restrict__ rv, unsigned short* __restrict__ x2h,
    unsigned short* __restrict__ x2l, int Nn)
{
    int d = (int)((blockIdx.x * blockDim.x + threadIdx.x) >> 6);
    int lane = threadIdx.x & 63;
    if (d >= Nn) return;
    int beg = offs[d], end = offs[d + 1];
    const int sub = lane >> 4;
    const int cl = (lane & 15) * 8;
    const int cbase = 128 + cl;
    float acc[8] = {};
    for (int base = beg; base < end; base += 64) {
        int nc = end - base; if (nc > 64) nc = 64;
        int sj = 0; float wj = 0.f;
        if (lane < nc) { sj = esrc[base + lane]; wj = alph[base + lane]; }
        edge_chunk_fma<4, 256>(sj, wj, nc, sub, h1b, cbase, acc);
    }
#pragma unroll
    for (int i = 0; i < 8; ++i) {
        acc[i] += __shfl_xor(acc[i], 32);
        acc[i] += __shfl_xor(acc[i], 16);
    }
    if (lane < 16) {
        unsigned short hh[8], ll[8];
#pragma unroll
        for (int i = 0; i < 8; ++i) {
            int c = cbase + i;
            float v = acc[i] + b1[c];
            v = gamma[c] * (v - rm[c]) * rsqrtf(rv[c] + EPSBN) + beta[c];
            v = fmaxf(v, 0.f);
            splitf(v, hh[i], ll[i]);
        }
        *(uint4*)(x2h + (size_t)d * 256 + cbase) = *(uint4*)&hh[0];
        *(uint4*)(x2l + (size_t)d * 256 + cbase) = *(uint4*)&ll[0];
    }
}

// ---------------- SpMM layer 2 slice 0 + fused softmax ----------------------
__global__ __launch_bounds__(256) void spmm2_s0(
    const unsigned short* __restrict__ h2b, const float* __restrict__ asrc,
    const float* __restrict__ adst, const int* __restrict__ offs,
    const int* __restrict__ esrc, float* __restrict__ a2e,
    const float* __restrict__ b2, const float* __restrict__ gamma,
    const float* __restrict__ beta, const float* __restrict__ rm,
    const float* __restrict__ rv, float* __restrict__ x3, int Nn)
{
    int d = (int)((blockIdx.x * blockDim.x + threadIdx.x) >> 6);
    int lane = threadIdx.x & 63;
    if (d >= Nn) return;
    int beg = offs[d], end = offs[d + 1];
    int deg = end - beg;
    float ad = adst[d];
    const int sub = lane >> 3;
    const int cl = (lane & 7) * 8;
    float acc[8] = {};

    if (deg <= 64) {
        int sj = 0; float ev = -1e30f;
        if (lane < deg) {
            sj = esrc[beg + lane];
            float e = asrc[sj] + ad; ev = e > 0.f ? e : NEG_SLOPE * e;
        }
        float m = ev;
        for (int off = 32; off; off >>= 1) m = fmaxf(m, __shfl_xor(m, off));
        float p = (lane < deg) ? expf(ev - m) : 0.f;
        float s = p;
        for (int off = 32; off; off >>= 1) s += __shfl_xor(s, off);
        float w = p * (1.f / s);
        if (lane < deg) a2e[beg + lane] = w;
        edge_chunk_fma<8, 128>(sj, w, deg, sub, h2b, cl, acc);
    } else {
        float m = -1e30f;
        for (int j = beg + lane; j < end; j += 64) {
            int s = esrc[j];
            float e = asrc[s] + ad; e = e > 0.f ? e : NEG_SLOPE * e;
            m = fmaxf(m, e);
        }
        for (int off = 32; off; off >>= 1) m = fmaxf(m, __shfl_xor(m, off));
        float sd = 0.f;
        for (int j = beg + lane; j < end; j += 64) {
            int s = esrc[j];
            float e = asrc[s] + ad; e = e > 0.f ? e : NEG_SLOPE * e;
            sd += expf(e - m);
        }
        for (int off = 32; off; off >>= 1) sd += __shfl_xor(sd, off);
        float rd = 1.f / sd;
        for (int j = beg + lane; j < end; j += 64) {
            int s = esrc[j];
            float e = asrc[s] + ad; e = e > 0.f ? e : NEG_SLOPE * e;
            a2e[j] = expf(e - m) * rd;
        }
        for (int base = beg; base < end; base += 64) {
            int nc = end - base; if (nc > 64) nc = 64;
            int sj = 0; float wj = 0.f;
            if (lane < nc) { sj = esrc[base + lane]; wj = a2e[base + lane]; }
            edge_chunk_fma<8, 128>(sj, wj, nc, sub, h2b, cl, acc);
        }
    }
#pragma unroll
    for (int i = 0; i < 8; ++i) {
        acc[i] += __shfl_xor(acc[i], 32);
        acc[i] += __shfl_xor(acc[i], 16);
        acc[i] += __shfl_xor(acc[i], 8);
    }
    if (lane < 8) {
        float vv[8];
#pragma unroll
        for (int i = 0; i < 8; ++i) {
            int c = cl + i;
            float v = acc[i] + b2[c];
            v = gamma[c] * (v - rm[c]) * rsqrtf(rv[c] + EPSBN) + beta[c];
            vv[i] = fmaxf(v, 0.f);
        }
        *(float4*)(x3 + (size_t)d * 128 + cl)     = make_float4(vv[0], vv[1], vv[2], vv[3]);
        *(float4*)(x3 + (size_t)d * 128 + cl + 4) = make_float4(vv[4], vv[5], vv[6], vv[7]);
    }
}

// ---------------- SpMM layer 2 slice 1 ---------------------------------------
__global__ __launch_bounds__(256) void spmm2_s1(
    const unsigned short* __restrict__ h2b, const float* __restrict__ alph,
    const int* __restrict__ offs, const int* __restrict__ esrc,
    const float* __restrict__ b2, const float* __restrict__ gamma,
    const float* __restrict__ beta, const float* __restrict__ rm,
    const float* __restrict__ rv, float* __restrict__ x3, int Nn)
{
    int d = (int)((blockIdx.x * blockDim.x + threadIdx.x) >> 6);
    int lane = threadIdx.x & 63;
    if (d >= Nn) return;
    int beg = offs[d], end = offs[d + 1];
    const int sub = lane >> 3;
    const int cl = (lane & 7) * 8;
    const int cbase = 64 + cl;
    float acc[8] = {};
    for (int base = beg; base < end; base += 64) {
        int nc = end - base; if (nc > 64) nc = 64;
        int sj = 0; float wj = 0.f;
        if (lane < nc) { sj = esrc[base + lane]; wj = alph[base + lane]; }
        edge_chunk_fma<8, 128>(sj, wj, nc, sub, h2b, cbase, acc);
    }
#pragma unroll
    for (int i = 0; i < 8; ++i) {
        acc[i] += __shfl_xor(acc[i], 32);
        acc[i] += __shfl_xor(acc[i], 16);
        acc[i] += __shfl_xor(acc[i], 8);
    }
    if (lane < 8) {
        float vv[8];
#pragma unroll
        for (int i = 0; i < 8; ++i) {
            int c = cbase + i;
            float v = acc[i] + b2[c];
            v = gamma[c] * (v - rm[c]) * rsqrtf(rv[c] + EPSBN) + beta[c];
            vv[i] = fmaxf(v, 0.f);
        }
        *(float4*)(x3 + (size_t)d * 128 + cbase)     = make_float4(vv[0], vv[1], vv[2], vv[3]);
        *(float4*)(x3 + (size_t)d * 128 + cbase + 4) = make_float4(vv[4], vv[5], vv[6], vv[7]);
    }
}

// ---------------- global max pool -------------------------------------------
__global__ void pool_max(const float* __restrict__ x3, const int* __restrict__ batch,
                         float* __restrict__ out, int Nn)
{
    int idx = blockIdx.x * blockDim.x + threadIdx.x;
    if (idx >= Nn * 128) return;
    int n = idx >> 7, c = idx & 127;
    int g = batch[n];
    atomicMax((unsigned int*)out + (size_t)g * 128 + c, __float_as_uint(x3[idx]));
}

// ---------------------------------------------------------------------------
extern "C" void kernel_launch(void* const* d_in, const int* in_sizes, int n_in,
                              void* d_out, int out_size, void* d_ws, size_t ws_size,
                              hipStream_t stream)
{
    const float* x   = (const float*)d_in[0];
    const int*   ei  = (const int*)d_in[1];
    const int*   bat = (const int*)d_in[2];
    const float* W1  = (const float*)d_in[3];
    const float* as1 = (const float*)d_in[4];
    const float* ad1 = (const float*)d_in[5];
    const float* b1  = (const float*)d_in[6];
    const float* g1  = (const float*)d_in[7];
    const float* be1 = (const float*)d_in[8];
    const float* rm1 = (const float*)d_in[9];
    const float* rv1 = (const float*)d_in[10];
    const float* W2  = (const float*)d_in[11];
    const float* as2 = (const float*)d_in[12];
    const float* ad2 = (const float*)d_in[13];
    const float* b2  = (const float*)d_in[14];
    const float* g2  = (const float*)d_in[15];
    const float* be2 = (const float*)d_in[16];
    const float* rm2 = (const float*)d_in[17];
    const float* rv2 = (const float*)d_in[18];
    float* out = (float*)d_out;

    const int Nn = in_sizes[0] / 128;
    const int E  = in_sizes[1] / 2;
    const int E2 = E + Nn;

    char* p = (char*)d_ws;
    size_t off = 0;
    auto alloc = [&](size_t bytes) -> void* {
        void* r = p + off;
        off = (off + bytes + 255) & ~(size_t)255;
        return r;
    };
    unsigned short* xh    = (unsigned short*)alloc((size_t)Nn * 128 * 2);
    unsigned short* xl    = (unsigned short*)alloc((size_t)Nn * 128 * 2);
    unsigned short* w1th  = (unsigned short*)alloc(256 * 128 * 2);
    unsigned short* w1tl  = (unsigned short*)alloc(256 * 128 * 2);
    unsigned short* w2th  = (unsigned short*)alloc(128 * 256 * 2);
    unsigned short* w2tl  = (unsigned short*)alloc(128 * 256 * 2);
    unsigned short* h1b   = (unsigned short*)alloc((size_t)Nn * 256 * 2);
    unsigned short* x2h   = (unsigned short*)alloc((size_t)Nn * 256 * 2);
    unsigned short* x2l   = (unsigned short*)alloc((size_t)Nn * 256 * 2);
    unsigned short* h2b   = (unsigned short*)alloc((size_t)Nn * 128 * 2);
    float*          x3    = (float*)alloc((size_t)Nn * 128 * 4);
    float*          attnv = (float*)alloc((size_t)Nn * 6 * 4);   // asrc1,adst1,asrc2,adst2
    float*          asrc1 = attnv;
    float*          adst1 = attnv + (size_t)Nn * 2;
    float*          asrc2 = attnv + (size_t)Nn * 4;
    float*          adst2 = attnv + (size_t)Nn * 5;
    float*          a1h0  = (float*)alloc((size_t)E2 * 4);
    float*          a1h1  = (float*)alloc((size_t)E2 * 4);
    float*          a2e   = (float*)alloc((size_t)E2 * 4);
    int*            counts= (int*)alloc((size_t)Nn * 4);
    int*            erank = (int*)alloc((size_t)E2 * 4);
    int*            offs  = (int*)alloc((size_t)(Nn + 1) * 4);
    int*            bsum  = (int*)alloc(256 * 4);
    int*            boff  = (int*)alloc(256 * 4);
    int*            esrc  = (int*)alloc((size_t)E2 * 4);

    const int nb = (Nn + 255) / 256;
    const int nwB = (Nn + 3) / 4;
    const int gmB = (Nn + 127) / 128;

    hipMemsetAsync(counts, 0, (size_t)Nn * 4, stream);
    hipMemsetAsync(attnv, 0, (size_t)Nn * 6 * 4, stream);
    hipMemsetAsync(d_out, 0, (size_t)out_size * 4, stream);

    // ---- input splits
    split_x4<<<(Nn * 128 / 4 + 255) / 256, 256, 0, stream>>>(x, xh, xl, Nn * 128 / 4);
    split_w_both<<<(65536 + 255) / 256, 256, 0, stream>>>(W1, W2, w1th, w1tl, w2th, w2tl);

    // ---- CSR build
    count_edges<<<(E2 + 255) / 256, 256, 0, stream>>>(ei, E, Nn, counts, erank);
    scan_block<<<nb, 256, 0, stream>>>(counts, offs, bsum, Nn);
    scan_tops<<<1, 256, 0, stream>>>(bsum, boff, nb);
    add_offsets<<<(Nn + 255) / 256, 256, 0, stream>>>(offs, boff, Nn, E2);
    fill_edges<<<(E2 + 255) / 256, 256, 0, stream>>>(ei, E, Nn, offs, erank, esrc);

    // ---- layer 1: GEMM (+attn coef) then SpMM slices
    gemm_bf16_split_attn<<<dim3(gmB, 2), 256, 0, stream>>>(
        xh, xl, w1th, w1tl, h1b, as1, ad1, asrc1, adst1, Nn, 256, 128, 2);
    spmm1_s0<<<nwB, 256, 0, stream>>>(h1b, asrc1, adst1, offs, esrc, a1h0, a1h1,
                                      b1, g1, be1, rm1, rv1, x2h, x2l, Nn);
    spmm1_s1<<<nwB, 256, 0, stream>>>(h1b, a1h1, offs, esrc,
                                      b1, g1, be1, rm1, rv1, x2h, x2l, Nn);

    // ---- layer 2
    gemm_bf16_split_attn<<<dim3(gmB, 1), 256, 0, stream>>>(
        x2h, x2l, w2th, w2tl, h2b, as2, ad2, asrc2, adst2, Nn, 128, 256, 1);
    spmm2_s0<<<nwB, 256, 0, stream>>>(h2b, asrc2, adst2, offs, esrc, a2e,
                                      b2, g2, be2, rm2, rv2, x3, Nn);
    spmm2_s1<<<nwB, 256, 0, stream>>>(h2b, a2e, offs, esrc,
                                      b2, g2, be2, rm2, rv2, x3, Nn);

    // ---- global max pool
    pool_max<<<((Nn * 128) + 255) / 256, 256, 0, stream>>>(x3, bat, out, Nn);
}

// Round 5
// 272.469 us; speedup vs baseline: 1.7910x; 1.1321x over previous
//
#include <hip/hip_runtime.h>
#include <hip/hip_bf16.h>
#include <math.h>

#define NEG_SLOPE 0.2f
#define EPSBN 1e-5f

typedef __attribute__((ext_vector_type(8))) short bf16x8;
typedef __attribute__((ext_vector_type(4))) float f32x4;

__device__ __forceinline__ float bfu2f(unsigned u_lo16) { return __uint_as_float(u_lo16 << 16); }
__device__ __forceinline__ unsigned short f2bf(float f) {
    return __bfloat16_as_ushort(__float2bfloat16(f));
}
__device__ __forceinline__ void splitf(float v, unsigned short &h, unsigned short &l) {
    __hip_bfloat16 hb = __float2bfloat16(v);
    float r = v - __bfloat162float(hb);
    h = __bfloat16_as_ushort(hb);
    l = __bfloat16_as_ushort(__float2bfloat16(r));
}

// ---------------- split kernels --------------------------------------------
__global__ void split_x4(const float* __restrict__ X, unsigned short* __restrict__ Xh,
                         unsigned short* __restrict__ Xl, int total4)
{
    int i = blockIdx.x * blockDim.x + threadIdx.x;
    if (i >= total4) return;
    float4 v = *(const float4*)(X + (size_t)i * 4);
    unsigned short h[4], l[4];
    splitf(v.x, h[0], l[0]); splitf(v.y, h[1], l[1]);
    splitf(v.z, h[2], l[2]); splitf(v.w, h[3], l[3]);
    *(uint2*)(Xh + (size_t)i * 4) = *(uint2*)h;
    *(uint2*)(Xl + (size_t)i * 4) = *(uint2*)l;
}

// both weights -> transposed split planes [N,K]
__global__ void split_w_both(const float* __restrict__ W1, const float* __restrict__ W2,
                             unsigned short* __restrict__ w1th, unsigned short* __restrict__ w1tl,
                             unsigned short* __restrict__ w2th, unsigned short* __restrict__ w2tl)
{
    int idx = blockIdx.x * blockDim.x + threadIdx.x;
    if (idx < 32768) {                      // W1 [128,256] -> [256,128]
        int nn = idx >> 7, k = idx & 127;
        unsigned short h, l; splitf(W1[(size_t)k * 256 + nn], h, l);
        w1th[idx] = h; w1tl[idx] = l;
    } else if (idx < 65536) {               // W2 [256,128] -> [128,256]
        int j = idx - 32768;
        int nn = j >> 8, k = j & 255;
        unsigned short h, l; splitf(W2[(size_t)k * 128 + nn], h, l);
        w2th[j] = h; w2tl[j] = l;
    }
}

// ---------------- MFMA GEMM + fused attention coefficients ------------------
__global__ __launch_bounds__(256) void gemm_bf16_split_attn(
    const unsigned short* __restrict__ Ah, const unsigned short* __restrict__ Al,
    const unsigned short* __restrict__ Bth, const unsigned short* __restrict__ Btl,
    unsigned short* __restrict__ Cb,
    const float* __restrict__ aSrc, const float* __restrict__ aDst,
    float* __restrict__ asrcOut, float* __restrict__ adstOut,
    int M, int N, int K, int heads)
{
    __shared__ unsigned short smem[4][128][32];  // Ah,Al,Bh,Bl tiles: 32 KiB
    const int tid = threadIdx.x;
    const int lane = tid & 63;
    const int wave = tid >> 6;
    const int fr = lane & 15, g = lane >> 4;
    const int wr = (wave >> 1) * 64, wc = (wave & 1) * 64;
    const int rowBase = blockIdx.x * 128, colBase = blockIdx.y * 128;

    f32x4 acc[4][4] = {};

    for (int kk = 0; kk < K; kk += 32) {
#pragma unroll
        for (int i = 0; i < 2; ++i) {
            int idx = tid + 256 * i;
            int r = idx >> 2, c = (idx & 3) * 8;
            int grow = rowBase + r;
            uint4 va_h, va_l;
            if (grow < M) {
                va_h = *(const uint4*)(Ah + (size_t)grow * K + kk + c);
                va_l = *(const uint4*)(Al + (size_t)grow * K + kk + c);
            } else {
                va_h = make_uint4(0, 0, 0, 0); va_l = make_uint4(0, 0, 0, 0);
            }
            *(uint4*)&smem[0][r][c] = va_h;
            *(uint4*)&smem[1][r][c] = va_l;
            int gcol = colBase + r;
            *(uint4*)&smem[2][r][c] = *(const uint4*)(Bth + (size_t)gcol * K + kk + c);
            *(uint4*)&smem[3][r][c] = *(const uint4*)(Btl + (size_t)gcol * K + kk + c);
        }
        __syncthreads();

        bf16x8 ah[4], al[4], bh[4], bl[4];
#pragma unroll
        for (int m = 0; m < 4; ++m) {
            ah[m] = *(const bf16x8*)&smem[0][wr + m * 16 + fr][g * 8];
            al[m] = *(const bf16x8*)&smem[1][wr + m * 16 + fr][g * 8];
        }
#pragma unroll
        for (int n = 0; n < 4; ++n) {
            bh[n] = *(const bf16x8*)&smem[2][wc + n * 16 + fr][g * 8];
            bl[n] = *(const bf16x8*)&smem[3][wc + n * 16 + fr][g * 8];
        }
#pragma unroll
        for (int m = 0; m < 4; ++m)
#pragma unroll
            for (int n = 0; n < 4; ++n) {
                acc[m][n] = __builtin_amdgcn_mfma_f32_16x16x32_bf16(ah[m], bh[n], acc[m][n], 0, 0, 0);
                acc[m][n] = __builtin_amdgcn_mfma_f32_16x16x32_bf16(ah[m], bl[n], acc[m][n], 0, 0, 0);
                acc[m][n] = __builtin_amdgcn_mfma_f32_16x16x32_bf16(al[m], bh[n], acc[m][n], 0, 0, 0);
            }
        __syncthreads();
    }

    // ---- fused attention coefficient partials (f32 accuracy)
    {
        const int head = colBase >> 7;
        float avs[4], avd[4];
#pragma unroll
        for (int n = 0; n < 4; ++n) {
            int col = colBase + wc + n * 16 + fr;
            avs[n] = aSrc[col]; avd[n] = aDst[col];
        }
#pragma unroll
        for (int m = 0; m < 4; ++m) {
            float ps[4], pd[4];
#pragma unroll
            for (int j = 0; j < 4; ++j) {
                ps[j] = acc[m][0][j] * avs[0] + acc[m][1][j] * avs[1]
                      + acc[m][2][j] * avs[2] + acc[m][3][j] * avs[3];
                pd[j] = acc[m][0][j] * avd[0] + acc[m][1][j] * avd[1]
                      + acc[m][2][j] * avd[2] + acc[m][3][j] * avd[3];
            }
#pragma unroll
            for (int off = 8; off; off >>= 1)
#pragma unroll
                for (int j = 0; j < 4; ++j) {
                    ps[j] += __shfl_xor(ps[j], off);
                    pd[j] += __shfl_xor(pd[j], off);
                }
            if (fr == 0) {
#pragma unroll
                for (int j = 0; j < 4; ++j) {
                    int grow = rowBase + wr + m * 16 + g * 4 + j;
                    if (grow < M) {
                        atomicAdd(asrcOut + (size_t)grow * heads + head, ps[j]);
                        atomicAdd(adstOut + (size_t)grow * heads + head, pd[j]);
                    }
                }
            }
        }
    }

    // ---- epilogue: LDS transpose, coalesced bf16 stores
    float* Cs = (float*)&smem[0][0][0];
    const int rl_w = (wr >> 6) * 16;
#pragma unroll
    for (int m = 0; m < 4; ++m) {
        __syncthreads();
#pragma unroll
        for (int n = 0; n < 4; ++n)
#pragma unroll
            for (int j = 0; j < 4; ++j)
                Cs[(rl_w + g * 4 + j) * 132 + wc + n * 16 + fr] = acc[m][n][j];
        __syncthreads();
        int rl = tid >> 3, c16 = (tid & 7) * 16;
        int grow = rowBase + (rl >> 4) * 64 + m * 16 + (rl & 15);
        if (grow < M) {
            unsigned short tmp[16];
#pragma unroll
            for (int i = 0; i < 16; ++i) tmp[i] = f2bf(Cs[rl * 132 + c16 + i]);
            *(uint4*)(Cb + (size_t)grow * N + colBase + c16)     = *(uint4*)&tmp[0];
            *(uint4*)(Cb + (size_t)grow * N + colBase + c16 + 8) = *(uint4*)&tmp[8];
        }
    }
}

// ---------------- CSR build -------------------------------------------------
__global__ void count_edges(const int* __restrict__ ei, int E, int Nn,
                            int* __restrict__ counts, int* __restrict__ erank)
{
    int e = blockIdx.x * blockDim.x + threadIdx.x;
    int E2 = E + Nn;
    if (e >= E2) return;
    int dst = (e < E) ? ei[E + e] : (e - E);
    erank[e] = atomicAdd(&counts[dst], 1);
}

__global__ __launch_bounds__(256) void scan_block(
    const int* __restrict__ counts, int* __restrict__ offs, int* __restrict__ bsum, int Nn)
{
    __shared__ int s[256];
    int i = blockIdx.x * 256 + threadIdx.x;
    int v = (i < Nn) ? counts[i] : 0;
    s[threadIdx.x] = v;
    __syncthreads();
    for (int off = 1; off < 256; off <<= 1) {
        int t = (threadIdx.x >= off) ? s[threadIdx.x - off] : 0;
        __syncthreads();
        s[threadIdx.x] += t;
        __syncthreads();
    }
    if (i < Nn) offs[i] = s[threadIdx.x] - v;
    if (threadIdx.x == 255) bsum[blockIdx.x] = s[255];
}

__global__ __launch_bounds__(256) void scan_tops(int* __restrict__ bsum, int* __restrict__ boff, int nb)
{
    __shared__ int s[256];
    int v = (threadIdx.x < nb) ? bsum[threadIdx.x] : 0;
    s[threadIdx.x] = v;
    __syncthreads();
    for (int off = 1; off < 256; off <<= 1) {
        int t = (threadIdx.x >= off) ? s[threadIdx.x - off] : 0;
        __syncthreads();
        s[threadIdx.x] += t;
        __syncthreads();
    }
    if (threadIdx.x < nb) boff[threadIdx.x] = s[threadIdx.x] - v;
}

__global__ void add_offsets(int* __restrict__ offs, const int* __restrict__ boff, int Nn, int E2)
{
    int i = blockIdx.x * blockDim.x + threadIdx.x;
    if (i < Nn) offs[i] += boff[i >> 8];
    if (i == 0) offs[Nn] = E2;
}

// atomic-free scatter using precomputed rank
__global__ void fill_edges(const int* __restrict__ ei, int E, int Nn,
                           const int* __restrict__ offs, const int* __restrict__ erank,
                           int* __restrict__ esrc)
{
    int e = blockIdx.x * blockDim.x + threadIdx.x;
    int E2 = E + Nn;
    if (e >= E2) return;
    int src, dst;
    if (e < E) { src = ei[e]; dst = ei[E + e]; }
    else       { src = e - E; dst = e - E; }
    esrc[offs[dst] + erank[e]] = src;
}

// ---------------- unpack-FMA of one gathered uint4 (8 bf16 ch) --------------
__device__ __forceinline__ void fma8(float wA, uint4 hv, float acc[8])
{
    acc[0] = fmaf(wA, bfu2f(hv.x & 0xffff), acc[0]);
    acc[1] = fmaf(wA, __uint_as_float(hv.x & 0xffff0000u), acc[1]);
    acc[2] = fmaf(wA, bfu2f(hv.y & 0xffff), acc[2]);
    acc[3] = fmaf(wA, __uint_as_float(hv.y & 0xffff0000u), acc[3]);
    acc[4] = fmaf(wA, bfu2f(hv.z & 0xffff), acc[4]);
    acc[5] = fmaf(wA, __uint_as_float(hv.z & 0xffff0000u), acc[5]);
    acc[6] = fmaf(wA, bfu2f(hv.w & 0xffff), acc[6]);
    acc[7] = fmaf(wA, __uint_as_float(hv.w & 0xffff0000u), acc[7]);
}

// ---------------- SpMM layer 1 (all 256 ch) + fused softmax ------------------
// wave per dst: 32 lanes x 8ch cover 256 ch; 2 edge subslots (sub = lane>>5).
__global__ __launch_bounds__(256) void spmm1(
    const unsigned short* __restrict__ h1b, const float* __restrict__ asrc,
    const float* __restrict__ adst, const int* __restrict__ offs,
    const int* __restrict__ esrc,
    const float* __restrict__ b1, const float* __restrict__ gamma,
    const float* __restrict__ beta, const float* __restrict__ rm,
    const float* __restrict__ rv, unsigned short* __restrict__ x2h,
    unsigned short* __restrict__ x2l, int Nn)
{
    int d = (int)((blockIdx.x * blockDim.x + threadIdx.x) >> 6);
    int lane = threadIdx.x & 63;
    if (d >= Nn) return;
    int beg = offs[d], end = offs[d + 1];
    int deg = end - beg;
    float ad0 = adst[d * 2], ad1 = adst[d * 2 + 1];
    const int sub = lane >> 5;            // edge subslot 0..1
    const int cgrp = lane & 31;           // channel group 0..31
    const int head = cgrp >> 4;           // 0 for ch<128, 1 for ch>=128
    const int cbyte = cgrp * 16;          // byte offset of 8 channels
    float acc[8] = {};

    if (deg <= 64) {
        int sj = 0; float e0 = -1e30f, e1 = -1e30f;
        if (lane < deg) {
            sj = esrc[beg + lane];
            float2 av = *(const float2*)(asrc + (size_t)sj * 2);
            e0 = av.x + ad0; e0 = e0 > 0.f ? e0 : NEG_SLOPE * e0;
            e1 = av.y + ad1; e1 = e1 > 0.f ? e1 : NEG_SLOPE * e1;
        }
        float m0 = e0, m1 = e1;
        for (int off = 32; off; off >>= 1) {
            m0 = fmaxf(m0, __shfl_xor(m0, off));
            m1 = fmaxf(m1, __shfl_xor(m1, off));
        }
        float p0 = (lane < deg) ? expf(e0 - m0) : 0.f;
        float p1 = (lane < deg) ? expf(e1 - m1) : 0.f;
        float s0 = p0, s1 = p1;
        for (int off = 32; off; off >>= 1) {
            s0 += __shfl_xor(s0, off);
            s1 += __shfl_xor(s1, off);
        }
        float w0 = p0 * (1.f / s0), w1 = p1 * (1.f / s1);
        for (int t = 0; t < deg; t += 2) {
            int e = t + sub;
            int sA = __shfl(sj, e);
            float w0A = __shfl(w0, e), w1A = __shfl(w1, e);
            float wA = head ? w1A : w0A;
            uint4 hv = *(const uint4*)((const char*)h1b + sA * 512 + cbyte);
            fma8(wA, hv, acc);
        }
    } else {
        float m0 = -1e30f, m1 = -1e30f;
        for (int j = beg + lane; j < end; j += 64) {
            int s = esrc[j];
            float2 av = *(const float2*)(asrc + (size_t)s * 2);
            float e0 = av.x + ad0; e0 = e0 > 0.f ? e0 : NEG_SLOPE * e0;
            float e1 = av.y + ad1; e1 = e1 > 0.f ? e1 : NEG_SLOPE * e1;
            m0 = fmaxf(m0, e0); m1 = fmaxf(m1, e1);
        }
        for (int off = 32; off; off >>= 1) {
            m0 = fmaxf(m0, __shfl_xor(m0, off));
            m1 = fmaxf(m1, __shfl_xor(m1, off));
        }
        float s0 = 0.f, s1 = 0.f;
        for (int j = beg + lane; j < end; j += 64) {
            int s = esrc[j];
            float2 av = *(const float2*)(asrc + (size_t)s * 2);
            float e0 = av.x + ad0; e0 = e0 > 0.f ? e0 : NEG_SLOPE * e0;
            float e1 = av.y + ad1; e1 = e1 > 0.f ? e1 : NEG_SLOPE * e1;
            s0 += expf(e0 - m0); s1 += expf(e1 - m1);
        }
        for (int off = 32; off; off >>= 1) {
            s0 += __shfl_xor(s0, off);
            s1 += __shfl_xor(s1, off);
        }
        float rd0 = 1.f / s0, rd1 = 1.f / s1;
        for (int base = beg; base < end; base += 64) {
            int nc = end - base; if (nc > 64) nc = 64;
            int sj = 0; float w0 = 0.f, w1 = 0.f;
            if (lane < nc) {
                sj = esrc[base + lane];
                float2 av = *(const float2*)(asrc + (size_t)sj * 2);
                float e0 = av.x + ad0; e0 = e0 > 0.f ? e0 : NEG_SLOPE * e0;
                float e1 = av.y + ad1; e1 = e1 > 0.f ? e1 : NEG_SLOPE * e1;
                w0 = expf(e0 - m0) * rd0;
                w1 = expf(e1 - m1) * rd1;
            }
            for (int t = 0; t < nc; t += 2) {
                int e = t + sub;
                int sA = __shfl(sj, e);
                float w0A = __shfl(w0, e), w1A = __shfl(w1, e);
                float wA = head ? w1A : w0A;
                uint4 hv = *(const uint4*)((const char*)h1b + sA * 512 + cbyte);
                fma8(wA, hv, acc);
            }
        }
    }
#pragma unroll
    for (int i = 0; i < 8; ++i) acc[i] += __shfl_xor(acc[i], 32);
    if (lane < 32) {
        int cl = cgrp * 8;
        unsigned short hh[8], ll[8];
#pragma unroll
        for (int i = 0; i < 8; ++i) {
            int c = cl + i;
            float v = acc[i] + b1[c];
            v = gamma[c] * (v - rm[c]) * rsqrtf(rv[c] + EPSBN) + beta[c];
            v = fmaxf(v, 0.f);
            splitf(v, hh[i], ll[i]);
        }
        *(uint4*)(x2h + (size_t)d * 256 + cl) = *(uint4*)&hh[0];
        *(uint4*)(x2l + (size_t)d * 256 + cl) = *(uint4*)&ll[0];
    }
}

// ---------------- SpMM layer 2 (all 128 ch) + fused softmax ------------------
// wave per dst: 16 lanes x 8ch cover 128 ch; 4 edge subslots (sub = lane>>4).
__global__ __launch_bounds__(256) void spmm2(
    const unsigned short* __restrict__ h2b, const float* __restrict__ asrc,
    const float* __restrict__ adst, const int* __restrict__ offs,
    const int* __restrict__ esrc,
    const float* __restrict__ b2, const float* __restrict__ gamma,
    const float* __restrict__ beta, const float* __restrict__ rm,
    const float* __restrict__ rv, float* __restrict__ x3, int Nn)
{
    int d = (int)((blockIdx.x * blockDim.x + threadIdx.x) >> 6);
    int lane = threadIdx.x & 63;
    if (d >= Nn) return;
    int beg = offs[d], end = offs[d + 1];
    int deg = end - beg;
    float ad = adst[d];
    const int sub = lane >> 4;            // edge subslot 0..3
    const int cgrp = lane & 15;
    const int cbyte = cgrp * 16;
    float acc[8] = {};

    if (deg <= 64) {
        int sj = 0; float ev = -1e30f;
        if (lane < deg) {
            sj = esrc[beg + lane];
            float e = asrc[sj] + ad; ev = e > 0.f ? e : NEG_SLOPE * e;
        }
        float m = ev;
        for (int off = 32; off; off >>= 1) m = fmaxf(m, __shfl_xor(m, off));
        float p = (lane < deg) ? expf(ev - m) : 0.f;
        float s = p;
        for (int off = 32; off; off >>= 1) s += __shfl_xor(s, off);
        float w = p * (1.f / s);
        for (int t = 0; t < deg; t += 4) {
            int e = t + sub;
            int sA = __shfl(sj, e);
            float wA = __shfl(w, e);
            uint4 hv = *(const uint4*)((const char*)h2b + sA * 256 + cbyte);
            fma8(wA, hv, acc);
        }
    } else {
        float m = -1e30f;
        for (int j = beg + lane; j < end; j += 64) {
            int s = esrc[j];
            float e = asrc[s] + ad; e = e > 0.f ? e : NEG_SLOPE * e;
            m = fmaxf(m, e);
        }
        for (int off = 32; off; off >>= 1) m = fmaxf(m, __shfl_xor(m, off));
        float sd = 0.f;
        for (int j = beg + lane; j < end; j += 64) {
            int s = esrc[j];
            float e = asrc[s] + ad; e = e > 0.f ? e : NEG_SLOPE * e;
            sd += expf(e - m);
        }
        for (int off = 32; off; off >>= 1) sd += __shfl_xor(sd, off);
        float rd = 1.f / sd;
        for (int base = beg; base < end; base += 64) {
            int nc = end - base; if (nc > 64) nc = 64;
            int sj = 0; float wj = 0.f;
            if (lane < nc) {
                sj = esrc[base + lane];
                float e = asrc[sj] + ad; e = e > 0.f ? e : NEG_SLOPE * e;
                wj = expf(e - m) * rd;
            }
            for (int t = 0; t < nc; t += 4) {
                int e = t + sub;
                int sA = __shfl(sj, e);
                float wA = __shfl(wj, e);
                uint4 hv = *(const uint4*)((const char*)h2b + sA * 256 + cbyte);
                fma8(wA, hv, acc);
            }
        }
    }
#pragma unroll
    for (int i = 0; i < 8; ++i) {
        acc[i] += __shfl_xor(acc[i], 32);
        acc[i] += __shfl_xor(acc[i], 16);
    }
    if (lane < 16) {
        int cl = cgrp * 8;
        float vv[8];
#pragma unroll
        for (int i = 0; i < 8; ++i) {
            int c = cl + i;
            float v = acc[i] + b2[c];
            v = gamma[c] * (v - rm[c]) * rsqrtf(rv[c] + EPSBN) + beta[c];
            vv[i] = fmaxf(v, 0.f);
        }
        *(float4*)(x3 + (size_t)d * 128 + cl)     = make_float4(vv[0], vv[1], vv[2], vv[3]);
        *(float4*)(x3 + (size_t)d * 128 + cl + 4) = make_float4(vv[4], vv[5], vv[6], vv[7]);
    }
}

// ---------------- global max pool -------------------------------------------
__global__ void pool_max(const float* __restrict__ x3, const int* __restrict__ batch,
                         float* __restrict__ out, int Nn)
{
    int idx = blockIdx.x * blockDim.x + threadIdx.x;
    if (idx >= Nn * 128) return;
    int n = idx >> 7, c = idx & 127;
    int g = batch[n];
    atomicMax((unsigned int*)out + (size_t)g * 128 + c, __float_as_uint(x3[idx]));
}

// ---------------------------------------------------------------------------
extern "C" void kernel_launch(void* const* d_in, const int* in_sizes, int n_in,
                              void* d_out, int out_size, void* d_ws, size_t ws_size,
                              hipStream_t stream)
{
    const float* x   = (const float*)d_in[0];
    const int*   ei  = (const int*)d_in[1];
    const int*   bat = (const int*)d_in[2];
    const float* W1  = (const float*)d_in[3];
    const float* as1 = (const float*)d_in[4];
    const float* ad1 = (const float*)d_in[5];
    const float* b1  = (const float*)d_in[6];
    const float* g1  = (const float*)d_in[7];
    const float* be1 = (const float*)d_in[8];
    const float* rm1 = (const float*)d_in[9];
    const float* rv1 = (const float*)d_in[10];
    const float* W2  = (const float*)d_in[11];
    const float* as2 = (const float*)d_in[12];
    const float* ad2 = (const float*)d_in[13];
    const float* b2  = (const float*)d_in[14];
    const float* g2  = (const float*)d_in[15];
    const float* be2 = (const float*)d_in[16];
    const float* rm2 = (const float*)d_in[17];
    const float* rv2 = (const float*)d_in[18];
    float* out = (float*)d_out;

    const int Nn = in_sizes[0] / 128;
    const int E  = in_sizes[1] / 2;
    const int E2 = E + Nn;

    char* p = (char*)d_ws;
    size_t off = 0;
    auto alloc = [&](size_t bytes) -> void* {
        void* r = p + off;
        off = (off + bytes + 255) & ~(size_t)255;
        return r;
    };
    unsigned short* xh    = (unsigned short*)alloc((size_t)Nn * 128 * 2);
    unsigned short* xl    = (unsigned short*)alloc((size_t)Nn * 128 * 2);
    unsigned short* w1th  = (unsigned short*)alloc(256 * 128 * 2);
    unsigned short* w1tl  = (unsigned short*)alloc(256 * 128 * 2);
    unsigned short* w2th  = (unsigned short*)alloc(128 * 256 * 2);
    unsigned short* w2tl  = (unsigned short*)alloc(128 * 256 * 2);
    unsigned short* h1b   = (unsigned short*)alloc((size_t)Nn * 256 * 2);
    unsigned short* x2h   = (unsigned short*)alloc((size_t)Nn * 256 * 2);
    unsigned short* x2l   = (unsigned short*)alloc((size_t)Nn * 256 * 2);
    unsigned short* h2b   = (unsigned short*)alloc((size_t)Nn * 128 * 2);
    float*          x3    = (float*)alloc((size_t)Nn * 128 * 4);
    float*          attnv = (float*)alloc((size_t)Nn * 6 * 4);   // asrc1,adst1,asrc2,adst2
    float*          asrc1 = attnv;
    float*          adst1 = attnv + (size_t)Nn * 2;
    float*          asrc2 = attnv + (size_t)Nn * 4;
    float*          adst2 = attnv + (size_t)Nn * 5;
    int*            counts= (int*)alloc((size_t)Nn * 4);
    int*            erank = (int*)alloc((size_t)E2 * 4);
    int*            offs  = (int*)alloc((size_t)(Nn + 1) * 4);
    int*            bsum  = (int*)alloc(256 * 4);
    int*            boff  = (int*)alloc(256 * 4);
    int*            esrc  = (int*)alloc((size_t)E2 * 4);

    const int nb = (Nn + 255) / 256;
    const int nwB = (Nn + 3) / 4;
    const int gmB = (Nn + 127) / 128;

    hipMemsetAsync(counts, 0, (size_t)Nn * 4, stream);
    hipMemsetAsync(attnv, 0, (size_t)Nn * 6 * 4, stream);
    hipMemsetAsync(d_out, 0, (size_t)out_size * 4, stream);

    // ---- input splits
    split_x4<<<(Nn * 128 / 4 + 255) / 256, 256, 0, stream>>>(x, xh, xl, Nn * 128 / 4);
    split_w_both<<<(65536 + 255) / 256, 256, 0, stream>>>(W1, W2, w1th, w1tl, w2th, w2tl);

    // ---- CSR build
    count_edges<<<(E2 + 255) / 256, 256, 0, stream>>>(ei, E, Nn, counts, erank);
    scan_block<<<nb, 256, 0, stream>>>(counts, offs, bsum, Nn);
    scan_tops<<<1, 256, 0, stream>>>(bsum, boff, nb);
    add_offsets<<<(Nn + 255) / 256, 256, 0, stream>>>(offs, boff, Nn, E2);
    fill_edges<<<(E2 + 255) / 256, 256, 0, stream>>>(ei, E, Nn, offs, erank, esrc);

    // ---- layer 1: GEMM (+attn coef) then SpMM
    gemm_bf16_split_attn<<<dim3(gmB, 2), 256, 0, stream>>>(
        xh, xl, w1th, w1tl, h1b, as1, ad1, asrc1, adst1, Nn, 256, 128, 2);
    spmm1<<<nwB, 256, 0, stream>>>(h1b, asrc1, adst1, offs, esrc,
                                   b1, g1, be1, rm1, rv1, x2h, x2l, Nn);

    // ---- layer 2
    gemm_bf16_split_attn<<<dim3(gmB, 1), 256, 0, stream>>>(
        x2h, x2l, w2th, w2tl, h2b, as2, ad2, asrc2, adst2, Nn, 128, 256, 1);
    spmm2<<<nwB, 256, 0, stream>>>(h2b, asrc2, adst2, offs, esrc,
                                   b2, g2, be2, rm2, rv2, x3, Nn);

    // ---- global max pool
    pool_max<<<((Nn * 128) + 255) / 256, 256, 0, stream>>>(x3, bat, out, Nn);
}